// Round 18
// baseline (376.528 us; speedup 1.0000x reference)
//
#include <hip/hip_runtime.h>

#define SEQ 8192
#define DIM 1280
#define NHEADS 16
#define HD 80
#define HDP 96
#define NSEG 8
#define SEG 1024
#define KVB 64
#define NSTEP (SEG / KVB)
#define PST 72

typedef float f32x4 __attribute__((ext_vector_type(4)));
typedef short bf16x8 __attribute__((ext_vector_type(8)));
typedef unsigned int u32;

__device__ __forceinline__ float fast_exp2(float x) {
  return __builtin_amdgcn_exp2f(x);
}

__device__ __forceinline__ short f2bf(float f) {
  unsigned int u = __builtin_bit_cast(unsigned int, f);
  u = (u + 0x7fff + ((u >> 16) & 1)) >> 16;
  return (short)u;
}

__device__ __forceinline__ float bf2f(short s) {
  u32 u = ((u32)(unsigned short)s) << 16;
  return __builtin_bit_cast(float, u);
}

// packed f32x2 -> bf16x2 (RNE), D.lo = S0, D.hi = S1. No builtin on gfx950.
__device__ __forceinline__ u32 cvt_pk_bf16(float lo, float hi) {
  u32 r;
  asm("v_cvt_pk_bf16_f32 %0, %1, %2" : "=v"(r) : "v"(lo), "v"(hi));
  return r;
}

typedef __attribute__((address_space(1))) const unsigned int glds_src_t;
typedef __attribute__((address_space(3))) unsigned int glds_dst_t;
__device__ __forceinline__ void gload_lds16(const void* g, void* l) {
  __builtin_amdgcn_global_load_lds((glds_src_t*)g, (glds_dst_t*)l, 16, 0, 0);
}

// ---------------- generic f32 -> bf16 cast (vectorized) ----------------
__global__ void cast_f32_bf16(const float* __restrict__ in, short* __restrict__ out, int n) {
  int n4 = n >> 2;
  for (int i = blockIdx.x * blockDim.x + threadIdx.x; i < n4; i += gridDim.x * blockDim.x) {
    float4 v = ((const float4*)in)[i];
    short4 o;
    o.x = f2bf(v.x); o.y = f2bf(v.y); o.z = f2bf(v.z); o.w = f2bf(v.w);
    ((short4*)out)[i] = o;
  }
}

// ========== 256x128 bf16 GEMM, B^T (N,K), single-buf BK=64, 2 blocks/CU ==========
// 512 thr / 8 waves (wm 2 x wn 4); per-wave output 128x32 (acc[8][2], 64 VGPR).
// Single-buffered LDS (48 KB) -> 2 blocks/CU co-resident: while one block
// drains its stage at the barrier, the other issues MFMA (m97/m114 implicit
// cross-block overlap — the only mechanism measured >600 TF without the
// full HK phase schedule). Intensity 85 FLOP/staged-byte vs 64 for 128sq.
// Involution chunk-XOR swizzle on stage source + ds_read (0 conflicts).
// XCD-contiguous 1D grid. bf16 output goes through an LDS-staged epilogue
// (padded stride 136) -> full-sector 256B row stores (fixes the 2x HBM
// write amplification of direct 32B-chunk bf16 stores, r17 WRITE=134MB).
__global__ __launch_bounds__(512, 2) void gemm_bt_bias(
    const short* __restrict__ A, const short* __restrict__ B,
    const float* __restrict__ bias, float* __restrict__ C,
    short* __restrict__ Cb, int M, int N, int K) {
  __shared__ short Sh[24576];  // 48 KB: A tile 256x64 @0, B tile 128x64 @16384
  int tid = threadIdx.x;
  int w = tid >> 6, l = tid & 63;
  int lrow = l & 15, lg = l >> 4;
  int wm = w >> 2, wn = w & 3;
  int bid = blockIdx.x;
  int cpx = gridDim.x >> 3;
  int lid = (bid & 7) * cpx + (bid >> 3);
  int ntx = N >> 7;
  int m0 = (lid / ntx) * 256, n0 = (lid % ntx) * 128;

  f32x4 acc[8][2] = {};

  const char* Abase = (const char*)A + (size_t)m0 * K * 2;
  const char* Bbase = (const char*)B + (size_t)n0 * K * 2;

  for (int k0 = 0; k0 < K; k0 += 64) {
    // stage A: 2048 slots (4 rounds), B: 1024 slots (2 rounds)
#pragma unroll
    for (int j = 0; j < 4; j++) {
      int c = j * 512 + tid;
      int row = c >> 3;
      int slc = (c & 7) ^ (row & 7);
      gload_lds16(Abase + (size_t)row * K * 2 + (size_t)k0 * 2 + slc * 16,
                  (char*)Sh + (j * 512 + w * 64) * 16);
    }
#pragma unroll
    for (int j = 0; j < 2; j++) {
      int c = j * 512 + tid;
      int row = c >> 3;
      int slc = (c & 7) ^ (row & 7);
      gload_lds16(Bbase + (size_t)row * K * 2 + (size_t)k0 * 2 + slc * 16,
                  (char*)Sh + 32768 + (j * 512 + w * 64) * 16);
    }
    asm volatile("s_waitcnt vmcnt(0)" ::: "memory");
    __builtin_amdgcn_s_barrier();
    asm volatile("" ::: "memory");
#pragma unroll
    for (int kk = 0; kk < 2; kk++) {
      bf16x8 a[8], b[2];
#pragma unroll
      for (int mt = 0; mt < 8; mt++) {
        int row = wm * 128 + mt * 16 + lrow;
        int p = (kk * 4 + lg) ^ (row & 7);
        a[mt] = *(const bf16x8*)&Sh[row * 64 + p * 8];
      }
#pragma unroll
      for (int nt = 0; nt < 2; nt++) {
        int row = wn * 32 + nt * 16 + lrow;
        int p = (kk * 4 + lg) ^ (row & 7);
        b[nt] = *(const bf16x8*)&Sh[16384 + row * 64 + p * 8];
      }
      __builtin_amdgcn_s_setprio(1);
#pragma unroll
      for (int mt = 0; mt < 8; mt++)
#pragma unroll
        for (int nt = 0; nt < 2; nt++)
          acc[mt][nt] = __builtin_amdgcn_mfma_f32_16x16x32_bf16(a[mt], b[nt], acc[mt][nt], 0, 0, 0);
      __builtin_amdgcn_s_setprio(0);
    }
    __builtin_amdgcn_s_barrier();
    asm volatile("" ::: "memory");
  }

  if (Cb) {
    // LDS-staged bf16 epilogue: two wm-halves; Ct = 128 rows x 128 cols,
    // padded stride 136 shorts (34.8 KB, reuses Sh).
#pragma unroll
    for (int half = 0; half < 2; half++) {
      __syncthreads();
      if (wm == half) {
#pragma unroll
        for (int mt = 0; mt < 8; mt++)
#pragma unroll
          for (int nt = 0; nt < 2; nt++) {
            int col = wn * 32 + nt * 16 + lrow;
            float bv = bias[n0 + col];
#pragma unroll
            for (int r = 0; r < 4; r++)
              Sh[(mt * 16 + lg * 4 + r) * 136 + col] = f2bf(acc[mt][nt][r] + bv);
          }
      }
      __syncthreads();
      // cooperative full-sector store: 128 rows x 256B, 16B/thread x 4
#pragma unroll
      for (int j = 0; j < 4; j++) {
        int c = j * 512 + tid;
        int row = c >> 4, ch = c & 15;
        *(uint4*)&Cb[(size_t)(m0 + half * 128 + row) * N + n0 + ch * 8] =
            *(const uint4*)&Sh[row * 136 + ch * 8];
      }
    }
  } else {
#pragma unroll
    for (int nt = 0; nt < 2; nt++) {
      int col = n0 + wn * 32 + nt * 16 + lrow;
      float bv = bias[col];
#pragma unroll
      for (int mt = 0; mt < 8; mt++) {
        int mrow = m0 + wm * 128 + mt * 16 + lg * 4;
#pragma unroll
        for (int r = 0; r < 4; r++)
          C[(size_t)(mrow + r) * N + col] = acc[mt][nt][r] + bv;
      }
    }
  }
}

// ---------------- RoPE for q,k (bf16 in, bf16 out, head-major, pad to 96) ----------------
__global__ void rope_qk(const short* __restrict__ qkv, const float* __restrict__ cosb,
                        const float* __restrict__ sinb, short* __restrict__ qg,
                        short* __restrict__ kg) {
  int t = blockIdx.x * blockDim.x + threadIdx.x;
  if (t >= SEQ * NHEADS * 40) return;
  int d = t % 40;
  int h = (t / 40) & 15;
  int s = t / 640;
  const short* row = qkv + (size_t)s * (3 * DIM);
  float c0 = cosb[s * HD + d], c1 = cosb[s * HD + d + 40];
  float s0 = sinb[s * HD + d], s1 = sinb[s * HD + d + 40];
  float x1 = bf2f(row[h * HD + d]), x2 = bf2f(row[h * HD + d + 40]);
  float q0 = x1 * c0 - x2 * s0;
  float q1 = x2 * c1 + x1 * s1;
  float y1 = bf2f(row[DIM + h * HD + d]), y2 = bf2f(row[DIM + h * HD + d + 40]);
  float k0 = y1 * c0 - y2 * s0;
  float k1 = y2 * c1 + y1 * s1;
  const float sc = 0.11180339887498949f * 1.4426950408889634f;
  size_t base = ((size_t)h * SEQ + s) * HDP;
  qg[base + d] = f2bf(q0 * sc);
  qg[base + d + 40] = f2bf(q1 * sc);
  kg[base + d] = f2bf(k0);
  kg[base + d + 40] = f2bf(k1);
  if (d < 16) { qg[base + 80 + d] = 0; kg[base + 80 + d] = 0; }
}

// ---------------- V transpose: qkv bf16 (S,3,H,80) -> vt bf16 (H,80,S) ----------------
__global__ void v_transpose(const short* __restrict__ qkv, short* __restrict__ vt) {
  __shared__ short T[16][72];
  int st = blockIdx.x, dt = blockIdx.y, h = blockIdx.z;
  int d0 = dt * 16, s0 = st * 64;
  int t = threadIdx.x;
  int dd = t & 15, ss = t >> 4;
#pragma unroll
  for (int j = 0; j < 4; j++) {
    int s = ss + j * 16;
    T[dd][s] = qkv[(size_t)(s0 + s) * (3 * DIM) + 2 * DIM + h * HD + d0 + dd];
  }
  __syncthreads();
  int s2 = t & 63, dr = t >> 6;
#pragma unroll
  for (int j = 0; j < 4; j++) {
    int d = dr + j * 4;
    vt[((size_t)(h * HD + d0 + d)) * SEQ + s0 + s2] = T[d][s2];
  }
}

// ---------------- flash attention v7 (unchanged from r16) ----------------
__global__ __launch_bounds__(512, 2) void attn_kernel(
    const short* __restrict__ qg, const short* __restrict__ kg,
    const short* __restrict__ vt, short* __restrict__ out) {
  __shared__ short Ks[2][64 * 128];
  __shared__ short Pl[8][32 * PST];
  int bid = blockIdx.x;
  int b = bid & 7, h = (bid >> 3) & 15, qt = bid >> 7;
  int tid = threadIdx.x;
  int w = tid >> 6, l = tid & 63;
  int lrow = l & 15, lg = l >> 4;
  int qbase_s = b * SEG + qt * 256 + w * 32;

  const short* qh = qg + (size_t)h * SEQ * HDP;
  const short* kh = kg + (size_t)h * SEQ * HDP;
  const short* vh = vt + (size_t)h * HD * SEQ;

#define STAGE_K(BUF, KEY0N)                                                    \
  {                                                                            \
    _Pragma("unroll") for (int sr = 0; sr < 2; sr++) {                         \
      int sbase = sr * 512 + w * 64;                                           \
      int ss = sbase + l;                                                      \
      int skey = ss >> 4, sc = ss & 15;                                        \
      int slc = sc ^ (skey & 7);                                               \
      const short* ssrc =                                                      \
          kh + (size_t)((KEY0N) + skey) * HDP + (slc < 12 ? slc * 8 : 0);      \
      gload_lds16(ssrc, (char*)&Ks[BUF][0] + sbase * 16);                      \
    }                                                                          \
  }

  bf16x8 qf[2][3];
#pragma unroll
  for (int mt = 0; mt < 2; mt++)
#pragma unroll
    for (int ks = 0; ks < 3; ks++)
      qf[mt][ks] = *(const bf16x8*)&qh[(size_t)(qbase_s + mt * 16 + lrow) * HDP + ks * 32 + lg * 8];

  f32x4 o[2][5] = {};
  float m_st[2] = {-1e30f, -1e30f};
  float l_st[2] = {0.f, 0.f};

  short* Pw = &Pl[w][0];

  STAGE_K(0, b * SEG);
  __syncthreads();

  for (int i = 0; i < NSTEP; i++) {
    int cur = i & 1;
    int key0 = b * SEG + i * KVB;
    if (i + 1 < NSTEP) {
      STAGE_K(cur ^ 1, key0 + KVB);
    }

    f32x4 sv[2][4] = {};
    __builtin_amdgcn_s_setprio(1);
#pragma unroll
    for (int kt = 0; kt < 4; kt++) {
      bf16x8 kf[3];
      int key = kt * 16 + lrow;
#pragma unroll
      for (int ks = 0; ks < 3; ks++) {
        int p = (ks * 4 + lg) ^ (key & 7);
        kf[ks] = *(const bf16x8*)&Ks[cur][key * 128 + p * 8];
      }
#pragma unroll
      for (int mt = 0; mt < 2; mt++)
#pragma unroll
        for (int ks = 0; ks < 3; ks++)
          sv[mt][kt] = __builtin_amdgcn_mfma_f32_16x16x32_bf16(kf[ks], qf[mt][ks], sv[mt][kt], 0, 0, 0);
    }
    __builtin_amdgcn_s_setprio(0);

    bf16x8 vf[5][2];
#pragma unroll
    for (int nt = 0; nt < 5; nt++)
#pragma unroll
      for (int ks = 0; ks < 2; ks++)
        vf[nt][ks] = *(const bf16x8*)&vh[(size_t)(nt * 16 + lrow) * SEQ + key0 + ks * 32 + lg * 8];

    float cm[2];
#pragma unroll
    for (int mt = 0; mt < 2; mt++) {
      float a0 = fmaxf(fmaxf(sv[mt][0][0], sv[mt][0][1]), fmaxf(sv[mt][0][2], sv[mt][0][3]));
      float a1 = fmaxf(fmaxf(sv[mt][1][0], sv[mt][1][1]), fmaxf(sv[mt][1][2], sv[mt][1][3]));
      float a2 = fmaxf(fmaxf(sv[mt][2][0], sv[mt][2][1]), fmaxf(sv[mt][2][2], sv[mt][2][3]));
      float a3 = fmaxf(fmaxf(sv[mt][3][0], sv[mt][3][1]), fmaxf(sv[mt][3][2], sv[mt][3][3]));
      float c = fmaxf(fmaxf(a0, a1), fmaxf(a2, a3));
      c = fmaxf(c, __shfl_xor(c, 16));
      c = fmaxf(c, __shfl_xor(c, 32));
      cm[mt] = c;
    }
    if (__any((cm[0] > m_st[0] + 8.f) || (cm[1] > m_st[1] + 8.f))) {
#pragma unroll
      for (int mt = 0; mt < 2; mt++) {
        float mn = fmaxf(m_st[mt], cm[mt]);
        float c = fast_exp2(m_st[mt] - mn);
        m_st[mt] = mn;
        l_st[mt] *= c;
        float cr[4];
#pragma unroll
        for (int r = 0; r < 4; r++) cr[r] = __shfl(c, lg * 4 + r);
#pragma unroll
        for (int nt = 0; nt < 5; nt++)
#pragma unroll
          for (int r = 0; r < 4; r++) o[mt][nt][r] *= cr[r];
      }
    }
#pragma unroll
    for (int mt = 0; mt < 2; mt++) {
      float rs = 0.f;
#pragma unroll
      for (int kt = 0; kt < 4; kt++) {
#pragma unroll
        for (int r = 0; r < 4; r++) {
          sv[mt][kt][r] = fast_exp2(sv[mt][kt][r] - m_st[mt]);
          rs += sv[mt][kt][r];
        }
        uint2 pk;
        pk.x = cvt_pk_bf16(sv[mt][kt][0], sv[mt][kt][1]);
        pk.y = cvt_pk_bf16(sv[mt][kt][2], sv[mt][kt][3]);
        *(uint2*)&Pw[(mt * 16 + lrow) * PST + kt * 16 + lg * 4] = pk;
      }
      rs += __shfl_xor(rs, 16);
      rs += __shfl_xor(rs, 32);
      l_st[mt] += rs;
    }

    bf16x8 pa[2][2];
#pragma unroll
    for (int mt = 0; mt < 2; mt++)
#pragma unroll
      for (int ks = 0; ks < 2; ks++)
        pa[mt][ks] = *(const bf16x8*)&Pw[(mt * 16 + lrow) * PST + ks * 32 + lg * 8];
    __builtin_amdgcn_s_setprio(1);
#pragma unroll
    for (int nt = 0; nt < 5; nt++)
#pragma unroll
      for (int mt = 0; mt < 2; mt++)
#pragma unroll
        for (int ks = 0; ks < 2; ks++)
          o[mt][nt] = __builtin_amdgcn_mfma_f32_16x16x32_bf16(pa[mt][ks], vf[nt][ks], o[mt][nt], 0, 0, 0);
    __builtin_amdgcn_s_setprio(0);

    __syncthreads();
  }

#pragma unroll
  for (int mt = 0; mt < 2; mt++) {
    float rl = 1.f / l_st[mt];
    float ir[4];
#pragma unroll
    for (int r = 0; r < 4; r++) ir[r] = __shfl(rl, lg * 4 + r);
#pragma unroll
    for (int r = 0; r < 4; r++) {
      int srow = qbase_s + mt * 16 + lg * 4 + r;
#pragma unroll
      for (int nt = 0; nt < 5; nt++)
        out[(size_t)srow * DIM + h * HD + nt * 16 + lrow] = f2bf(o[mt][nt][r] * ir[r]);
    }
  }
}

extern "C" void kernel_launch(void* const* d_in, const int* in_sizes, int n_in,
                              void* d_out, int out_size, void* d_ws, size_t ws_size,
                              hipStream_t stream) {
  const float* hidden = (const float*)d_in[0];
  const float* cosb = (const float*)d_in[1];
  const float* sinb = (const float*)d_in[2];
  const float* qkv_w = (const float*)d_in[3];
  const float* qkv_b = (const float*)d_in[4];
  const float* proj_w = (const float*)d_in[5];
  const float* proj_b = (const float*)d_in[6];

  char* ws = (char*)d_ws;
  short* qkv_bf = (short*)(ws);
  short* attn_o = (short*)(ws);
  short* wp_bf = (short*)(ws + 23068672);
  short* q_bf = (short*)(ws + 125829120);
  short* k_bf = (short*)(ws + 150994944);
  short* v_tb = (short*)(ws + 176160768);
  short* h_bf = (short*)(ws + 197132288);
  short* wq_bf = (short*)(ws + 218103808);

  cast_f32_bf16<<<4096, 256, 0, stream>>>(hidden, h_bf, SEQ * DIM);
  cast_f32_bf16<<<4096, 256, 0, stream>>>(qkv_w, wq_bf, 3 * DIM * DIM);
  gemm_bt_bias<<<960, 512, 0, stream>>>(h_bf, wq_bf, qkv_b, nullptr, qkv_bf, SEQ, 3 * DIM, DIM);
  rope_qk<<<20480, 256, 0, stream>>>(qkv_bf, cosb, sinb, q_bf, k_bf);
  v_transpose<<<dim3(128, 5, 16), 256, 0, stream>>>(qkv_bf, v_tb);
  cast_f32_bf16<<<2048, 256, 0, stream>>>(proj_w, wp_bf, DIM * DIM);
  attn_kernel<<<512, 512, 0, stream>>>(q_bf, k_bf, v_tb, attn_o);
  gemm_bt_bias<<<320, 512, 0, stream>>>(attn_o, wp_bf, proj_b, (float*)d_out, nullptr, SEQ, DIM, DIM);
}

// Round 19
// 313.244 us; speedup vs baseline: 1.2020x; 1.2020x over previous
//
#include <hip/hip_runtime.h>

#define SEQ 8192
#define DIM 1280
#define NHEADS 16
#define HD 80
#define HDP 96
#define NSEG 8
#define SEG 1024
#define KVB 64
#define NSTEP (SEG / KVB)
#define PST 72

typedef float f32x4 __attribute__((ext_vector_type(4)));
typedef short bf16x8 __attribute__((ext_vector_type(8)));
typedef unsigned int u32;

__device__ __forceinline__ float fast_exp2(float x) {
  return __builtin_amdgcn_exp2f(x);
}

__device__ __forceinline__ short f2bf(float f) {
  unsigned int u = __builtin_bit_cast(unsigned int, f);
  u = (u + 0x7fff + ((u >> 16) & 1)) >> 16;
  return (short)u;
}

__device__ __forceinline__ float bf2f(short s) {
  u32 u = ((u32)(unsigned short)s) << 16;
  return __builtin_bit_cast(float, u);
}

// packed f32x2 -> bf16x2 (RNE), D.lo = S0, D.hi = S1. No builtin on gfx950.
__device__ __forceinline__ u32 cvt_pk_bf16(float lo, float hi) {
  u32 r;
  asm("v_cvt_pk_bf16_f32 %0, %1, %2" : "=v"(r) : "v"(lo), "v"(hi));
  return r;
}

typedef __attribute__((address_space(1))) const unsigned int glds_src_t;
typedef __attribute__((address_space(3))) unsigned int glds_dst_t;
__device__ __forceinline__ void gload_lds16(const void* g, void* l) {
  __builtin_amdgcn_global_load_lds((glds_src_t*)g, (glds_dst_t*)l, 16, 0, 0);
}

// ---------------- generic f32 -> bf16 cast (vectorized) ----------------
__global__ void cast_f32_bf16(const float* __restrict__ in, short* __restrict__ out, int n) {
  int n4 = n >> 2;
  for (int i = blockIdx.x * blockDim.x + threadIdx.x; i < n4; i += gridDim.x * blockDim.x) {
    float4 v = ((const float4*)in)[i];
    short4 o;
    o.x = f2bf(v.x); o.y = f2bf(v.y); o.z = f2bf(v.z); o.w = f2bf(v.w);
    ((short4*)out)[i] = o;
  }
}

// ============ 256x256 bf16 GEMM, BK=64 dbuf + ONE-TILE-DEEP counted vmcnt ============
// 512 thr / 8 waves (2M x 4N), per-wave 128x64 out (acc[8][4], AGPR).
// Per tile t: stage FULL tile t+1 (8 gload_lds/wave) -> vmcnt(8) (waits
// tile t's loads, issued one full tile of compute earlier: 64 MFMA + 16
// ds_read_b128 per wave ~550cy cover vs ~600cy L3 latency) -> barrier ->
// 64 MFMA from buf[cur] -> barrier. Two barriers per 64 MFMA (half the
// 128sq rate) and no cold vmcnt(0) drain in the loop (r17's null cause).
// r17's verified stage/fragment math (refchecked) reused verbatim.
// bf16 output via LDS-staged epilogue -> full 512B row stores (r18-proven;
// kills the 2x partial-sector write amplification: 134MB -> 63MB).
__global__ __launch_bounds__(512, 1) void gemm256(
    const short* __restrict__ A, const short* __restrict__ B,
    const float* __restrict__ bias, float* __restrict__ C,
    short* __restrict__ Cb, int M, int N, int K) {
  __shared__ short As[2][16384];  // 64 KB
  __shared__ short Bs[2][16384];  // 64 KB
  int tid = threadIdx.x;
  int w = tid >> 6, l = tid & 63;
  int lrow = l & 15, lg = l >> 4;
  int wm = w >> 2, wn = w & 3;
  int bid = blockIdx.x;
  int cpx = gridDim.x >> 3;
  int lid = (bid & 7) * cpx + (bid >> 3);
  int ntx = N >> 8;
  int m0 = (lid / ntx) * 256, n0 = (lid % ntx) * 256;

  const short* Ablk = A + (size_t)m0 * K;
  const short* Bblk = B + (size_t)n0 * K;

  f32x4 acc[8][4] = {};

#define STG_HALF(LDSB, GBASE, HALF, K0)                                       \
  {                                                                           \
    _Pragma("unroll") for (int rr = 0; rr < 2; rr++) {                        \
      int sb = rr * 512 + w * 64;                                             \
      int ss2 = sb + l;                                                       \
      int rl = ss2 >> 3, cc = ss2 & 7;                                        \
      int sl = cc ^ (rl & 7);                                                 \
      const short* sp = (GBASE) + (size_t)((HALF)*128 + rl) * K + (K0) + sl * 8; \
      gload_lds16(sp, (char*)(LDSB) + (HALF)*16384 + sb * 16);                \
    }                                                                         \
  }
#define LDA(MH, KS)                                                           \
  _Pragma("unroll") for (int mt = 0; mt < 4; mt++) {                          \
    int rowa = wm * 128 + ((MH)*4 + mt) * 16 + lrow;                          \
    int pa_ = ((KS)*4 + lg) ^ (rowa & 7);                                     \
    a[mt] = *(const bf16x8*)&As[cur][rowa * 64 + pa_ * 8];                    \
  }
#define LDB(KS)                                                               \
  _Pragma("unroll") for (int nt = 0; nt < 4; nt++) {                          \
    int rowb = wn * 64 + nt * 16 + lrow;                                      \
    int pb_ = ((KS)*4 + lg) ^ (rowb & 7);                                     \
    b[nt] = *(const bf16x8*)&Bs[cur][rowb * 64 + pb_ * 8];                    \
  }
#define MFMA16(MH)                                                            \
  _Pragma("unroll") for (int mt = 0; mt < 4; mt++)                            \
      _Pragma("unroll") for (int nt = 0; nt < 4; nt++)                        \
          acc[(MH)*4 + mt][nt] = __builtin_amdgcn_mfma_f32_16x16x32_bf16(     \
              a[mt], b[nt], acc[(MH)*4 + mt][nt], 0, 0, 0);

  // prologue: stage tile 0 into buf0, cold drain once
  {
    short* Ad = &As[0][0];
    short* Bd = &Bs[0][0];
    STG_HALF(Ad, Ablk, 0, 0);
    STG_HALF(Ad, Ablk, 1, 0);
    STG_HALF(Bd, Bblk, 0, 0);
    STG_HALF(Bd, Bblk, 1, 0);
  }
  asm volatile("s_waitcnt vmcnt(0)" ::: "memory");
  __builtin_amdgcn_s_barrier();
  asm volatile("" ::: "memory");

  int NT = K >> 6;
  for (int t = 0; t < NT; ++t) {
    int cur = t & 1;
    if (t + 1 < NT) {
      // stage FULL tile t+1 into buf[cur^1] (its tile-(t-1) reads finished
      // at the previous end-barrier), then wait only the previous tile's
      // 8 loads: the 8 just issued stay in flight across the barrier.
      short* Ad = &As[cur ^ 1][0];
      short* Bd = &Bs[cur ^ 1][0];
      int k1 = (t + 1) << 6;
      STG_HALF(Ad, Ablk, 0, k1);
      STG_HALF(Ad, Ablk, 1, k1);
      STG_HALF(Bd, Bblk, 0, k1);
      STG_HALF(Bd, Bblk, 1, k1);
      asm volatile("s_waitcnt vmcnt(8)" ::: "memory");
    } else {
      asm volatile("s_waitcnt vmcnt(0)" ::: "memory");
    }
    __builtin_amdgcn_s_barrier();  // buf[cur] fully populated across waves
    asm volatile("" ::: "memory");
    {
      bf16x8 a[4], b[4];
      __builtin_amdgcn_s_setprio(1);
      LDA(0, 0); LDB(0); MFMA16(0);
      LDA(1, 0); MFMA16(1);
      LDA(0, 1); LDB(1); MFMA16(0);
      LDA(1, 1); MFMA16(1);
      __builtin_amdgcn_s_setprio(0);
    }
    __builtin_amdgcn_s_barrier();  // all reads of buf[cur] done
    asm volatile("" ::: "memory");
  }

  if (Cb) {
    // LDS-staged bf16 epilogue: 4 sweeps of 64 rows x 256 cols, stride 264
    // shorts (16B-aligned rows), full 512B row stores. Reuses As (flat).
    short* E = &As[0][0];
#pragma unroll
    for (int s = 0; s < 4; s++) {
      __syncthreads();
      if (wm == (s >> 1)) {
#pragma unroll
        for (int mi = 0; mi < 4; mi++) {
          int mt2 = (s & 1) * 4 + mi;
#pragma unroll
          for (int nt = 0; nt < 4; nt++) {
            int col = wn * 64 + nt * 16 + lrow;
            float bv = bias[n0 + col];
#pragma unroll
            for (int r = 0; r < 4; r++)
              E[(mi * 16 + lg * 4 + r) * 264 + col] = f2bf(acc[mt2][nt][r] + bv);
          }
        }
      }
      __syncthreads();
#pragma unroll
      for (int j = 0; j < 4; j++) {
        int c = j * 512 + tid;
        int row = c >> 5, ch = c & 31;
        *(uint4*)&Cb[(size_t)(m0 + s * 64 + row) * N + n0 + ch * 8] =
            *(const uint4*)&E[row * 264 + ch * 8];
      }
    }
  } else {
#pragma unroll
    for (int nt = 0; nt < 4; nt++) {
      int col = n0 + wn * 64 + nt * 16 + lrow;
      float bv = bias[col];
#pragma unroll
      for (int mt = 0; mt < 8; mt++) {
        int mrow = m0 + wm * 128 + mt * 16 + lg * 4;
#pragma unroll
        for (int r = 0; r < 4; r++)
          C[(size_t)(mrow + r) * N + col] = acc[mt][nt][r] + bv;
      }
    }
  }
#undef STG_HALF
#undef LDA
#undef LDB
#undef MFMA16
}

// ---------------- 128x128 bf16 GEMM (proj; r16-proven) ----------------
__global__ __launch_bounds__(256) void gemm_bt_bias(
    const short* __restrict__ A, const short* __restrict__ B,
    const float* __restrict__ bias, float* __restrict__ C,
    short* __restrict__ Cb, int M, int N, int K) {
  __shared__ short As[2][128 * 64];
  __shared__ short Bs[2][128 * 64];
  int tid = threadIdx.x;
  int w = tid >> 6, l = tid & 63;
  int lrow = l & 15, lg = l >> 4;
  int bid = blockIdx.x;
  int cpx = gridDim.x >> 3;
  int lid = (bid & 7) * cpx + (bid >> 3);
  int ntx = N >> 7;
  int m0 = (lid / ntx) * 128, n0 = (lid % ntx) * 128;
  int wm = w & 1, wn = w >> 1;

  f32x4 acc[4][4] = {};

  const char* Abase = (const char*)A + (size_t)m0 * K * 2;
  const char* Bbase = (const char*)B + (size_t)n0 * K * 2;

#define STAGE_G(BUF, K0)                                                       \
  {                                                                            \
    _Pragma("unroll") for (int j = 0; j < 4; j++) {                            \
      int c = j * 256 + tid;                                                   \
      int row = c >> 3;                                                        \
      int slc = (c & 7) ^ (row & 7);                                           \
      size_t goff = (size_t)row * K * 2 + (size_t)(K0) * 2 + slc * 16;         \
      int loff = (j * 256 + w * 64) * 16;                                      \
      gload_lds16(Abase + goff, (char*)&As[BUF][0] + loff);                    \
      gload_lds16(Bbase + goff, (char*)&Bs[BUF][0] + loff);                    \
    }                                                                          \
  }

  STAGE_G(0, 0);
  asm volatile("s_waitcnt vmcnt(0)" ::: "memory");
  __builtin_amdgcn_s_barrier();
  asm volatile("" ::: "memory");

  for (int k0 = 0; k0 < K; k0 += 64) {
    int cur = (k0 >> 6) & 1;
    if (k0 + 64 < K) {
      STAGE_G(cur ^ 1, k0 + 64);
      asm volatile("s_waitcnt vmcnt(8)" ::: "memory");
    } else {
      asm volatile("s_waitcnt vmcnt(0)" ::: "memory");
    }
    __builtin_amdgcn_s_barrier();
    asm volatile("" ::: "memory");
#pragma unroll
    for (int kk = 0; kk < 2; kk++) {
      bf16x8 a[4], b[4];
#pragma unroll
      for (int mt = 0; mt < 4; mt++) {
        int row = wm * 64 + mt * 16 + lrow;
        int p = (kk * 4 + lg) ^ (row & 7);
        a[mt] = *(const bf16x8*)&As[cur][row * 64 + p * 8];
      }
#pragma unroll
      for (int nt = 0; nt < 4; nt++) {
        int row = wn * 64 + nt * 16 + lrow;
        int p = (kk * 4 + lg) ^ (row & 7);
        b[nt] = *(const bf16x8*)&Bs[cur][row * 64 + p * 8];
      }
#pragma unroll
      for (int mt = 0; mt < 4; mt++)
#pragma unroll
        for (int nt = 0; nt < 4; nt++)
          acc[mt][nt] = __builtin_amdgcn_mfma_f32_16x16x32_bf16(a[mt], b[nt], acc[mt][nt], 0, 0, 0);
    }
    __builtin_amdgcn_s_barrier();
    asm volatile("" ::: "memory");
  }

#pragma unroll
  for (int nt = 0; nt < 4; nt++) {
    int col = n0 + wn * 64 + nt * 16 + lrow;
    float bv = bias[col];
#pragma unroll
    for (int mt = 0; mt < 4; mt++) {
      int mrow = m0 + wm * 64 + mt * 16 + lg * 4;
      if (Cb) {
#pragma unroll
        for (int r = 0; r < 4; r++)
          Cb[(size_t)(mrow + r) * N + col] = f2bf(acc[mt][nt][r] + bv);
      } else {
#pragma unroll
        for (int r = 0; r < 4; r++)
          C[(size_t)(mrow + r) * N + col] = acc[mt][nt][r] + bv;
      }
    }
  }
}

// ---------------- RoPE for q,k (bf16 in, bf16 out, head-major, pad to 96) ----------------
__global__ void rope_qk(const short* __restrict__ qkv, const float* __restrict__ cosb,
                        const float* __restrict__ sinb, short* __restrict__ qg,
                        short* __restrict__ kg) {
  int t = blockIdx.x * blockDim.x + threadIdx.x;
  if (t >= SEQ * NHEADS * 40) return;
  int d = t % 40;
  int h = (t / 40) & 15;
  int s = t / 640;
  const short* row = qkv + (size_t)s * (3 * DIM);
  float c0 = cosb[s * HD + d], c1 = cosb[s * HD + d + 40];
  float s0 = sinb[s * HD + d], s1 = sinb[s * HD + d + 40];
  float x1 = bf2f(row[h * HD + d]), x2 = bf2f(row[h * HD + d + 40]);
  float q0 = x1 * c0 - x2 * s0;
  float q1 = x2 * c1 + x1 * s1;
  float y1 = bf2f(row[DIM + h * HD + d]), y2 = bf2f(row[DIM + h * HD + d + 40]);
  float k0 = y1 * c0 - y2 * s0;
  float k1 = y2 * c1 + y1 * s1;
  const float sc = 0.11180339887498949f * 1.4426950408889634f;
  size_t base = ((size_t)h * SEQ + s) * HDP;
  qg[base + d] = f2bf(q0 * sc);
  qg[base + d + 40] = f2bf(q1 * sc);
  kg[base + d] = f2bf(k0);
  kg[base + d + 40] = f2bf(k1);
  if (d < 16) { qg[base + 80 + d] = 0; kg[base + 80 + d] = 0; }
}

// ---------------- V transpose: qkv bf16 (S,3,H,80) -> vt bf16 (H,80,S) ----------------
__global__ void v_transpose(const short* __restrict__ qkv, short* __restrict__ vt) {
  __shared__ short T[16][72];
  int st = blockIdx.x, dt = blockIdx.y, h = blockIdx.z;
  int d0 = dt * 16, s0 = st * 64;
  int t = threadIdx.x;
  int dd = t & 15, ss = t >> 4;
#pragma unroll
  for (int j = 0; j < 4; j++) {
    int s = ss + j * 16;
    T[dd][s] = qkv[(size_t)(s0 + s) * (3 * DIM) + 2 * DIM + h * HD + d0 + dd];
  }
  __syncthreads();
  int s2 = t & 63, dr = t >> 6;
#pragma unroll
  for (int j = 0; j < 4; j++) {
    int d = dr + j * 4;
    vt[((size_t)(h * HD + d0 + d)) * SEQ + s0 + s2] = T[d][s2];
  }
}

// ---------------- flash attention v7 (r16-proven, unchanged) ----------------
__global__ __launch_bounds__(512, 2) void attn_kernel(
    const short* __restrict__ qg, const short* __restrict__ kg,
    const short* __restrict__ vt, short* __restrict__ out) {
  __shared__ short Ks[2][64 * 128];
  __shared__ short Pl[8][32 * PST];
  int bid = blockIdx.x;
  int b = bid & 7, h = (bid >> 3) & 15, qt = bid >> 7;
  int tid = threadIdx.x;
  int w = tid >> 6, l = tid & 63;
  int lrow = l & 15, lg = l >> 4;
  int qbase_s = b * SEG + qt * 256 + w * 32;

  const short* qh = qg + (size_t)h * SEQ * HDP;
  const short* kh = kg + (size_t)h * SEQ * HDP;
  const short* vh = vt + (size_t)h * HD * SEQ;

#define STAGE_K(BUF, KEY0N)                                                    \
  {                                                                            \
    _Pragma("unroll") for (int sr = 0; sr < 2; sr++) {                         \
      int sbase = sr * 512 + w * 64;                                           \
      int ss = sbase + l;                                                      \
      int skey = ss >> 4, sc = ss & 15;                                        \
      int slc = sc ^ (skey & 7);                                               \
      const short* ssrc =                                                      \
          kh + (size_t)((KEY0N) + skey) * HDP + (slc < 12 ? slc * 8 : 0);      \
      gload_lds16(ssrc, (char*)&Ks[BUF][0] + sbase * 16);                      \
    }                                                                          \
  }

  bf16x8 qf[2][3];
#pragma unroll
  for (int mt = 0; mt < 2; mt++)
#pragma unroll
    for (int ks = 0; ks < 3; ks++)
      qf[mt][ks] = *(const bf16x8*)&qh[(size_t)(qbase_s + mt * 16 + lrow) * HDP + ks * 32 + lg * 8];

  f32x4 o[2][5] = {};
  float m_st[2] = {-1e30f, -1e30f};
  float l_st[2] = {0.f, 0.f};

  short* Pw = &Pl[w][0];

  STAGE_K(0, b * SEG);
  __syncthreads();

  for (int i = 0; i < NSTEP; i++) {
    int cur = i & 1;
    int key0 = b * SEG + i * KVB;
    if (i + 1 < NSTEP) {
      STAGE_K(cur ^ 1, key0 + KVB);
    }

    f32x4 sv[2][4] = {};
    __builtin_amdgcn_s_setprio(1);
#pragma unroll
    for (int kt = 0; kt < 4; kt++) {
      bf16x8 kf[3];
      int key = kt * 16 + lrow;
#pragma unroll
      for (int ks = 0; ks < 3; ks++) {
        int p = (ks * 4 + lg) ^ (key & 7);
        kf[ks] = *(const bf16x8*)&Ks[cur][key * 128 + p * 8];
      }
#pragma unroll
      for (int mt = 0; mt < 2; mt++)
#pragma unroll
        for (int ks = 0; ks < 3; ks++)
          sv[mt][kt] = __builtin_amdgcn_mfma_f32_16x16x32_bf16(kf[ks], qf[mt][ks], sv[mt][kt], 0, 0, 0);
    }
    __builtin_amdgcn_s_setprio(0);

    bf16x8 vf[5][2];
#pragma unroll
    for (int nt = 0; nt < 5; nt++)
#pragma unroll
      for (int ks = 0; ks < 2; ks++)
        vf[nt][ks] = *(const bf16x8*)&vh[(size_t)(nt * 16 + lrow) * SEQ + key0 + ks * 32 + lg * 8];

    float cm[2];
#pragma unroll
    for (int mt = 0; mt < 2; mt++) {
      float a0 = fmaxf(fmaxf(sv[mt][0][0], sv[mt][0][1]), fmaxf(sv[mt][0][2], sv[mt][0][3]));
      float a1 = fmaxf(fmaxf(sv[mt][1][0], sv[mt][1][1]), fmaxf(sv[mt][1][2], sv[mt][1][3]));
      float a2 = fmaxf(fmaxf(sv[mt][2][0], sv[mt][2][1]), fmaxf(sv[mt][2][2], sv[mt][2][3]));
      float a3 = fmaxf(fmaxf(sv[mt][3][0], sv[mt][3][1]), fmaxf(sv[mt][3][2], sv[mt][3][3]));
      float c = fmaxf(fmaxf(a0, a1), fmaxf(a2, a3));
      c = fmaxf(c, __shfl_xor(c, 16));
      c = fmaxf(c, __shfl_xor(c, 32));
      cm[mt] = c;
    }
    if (__any((cm[0] > m_st[0] + 8.f) || (cm[1] > m_st[1] + 8.f))) {
#pragma unroll
      for (int mt = 0; mt < 2; mt++) {
        float mn = fmaxf(m_st[mt], cm[mt]);
        float c = fast_exp2(m_st[mt] - mn);
        m_st[mt] = mn;
        l_st[mt] *= c;
        float cr[4];
#pragma unroll
        for (int r = 0; r < 4; r++) cr[r] = __shfl(c, lg * 4 + r);
#pragma unroll
        for (int nt = 0; nt < 5; nt++)
#pragma unroll
          for (int r = 0; r < 4; r++) o[mt][nt][r] *= cr[r];
      }
    }
#pragma unroll
    for (int mt = 0; mt < 2; mt++) {
      float rs = 0.f;
#pragma unroll
      for (int kt = 0; kt < 4; kt++) {
#pragma unroll
        for (int r = 0; r < 4; r++) {
          sv[mt][kt][r] = fast_exp2(sv[mt][kt][r] - m_st[mt]);
          rs += sv[mt][kt][r];
        }
        uint2 pk;
        pk.x = cvt_pk_bf16(sv[mt][kt][0], sv[mt][kt][1]);
        pk.y = cvt_pk_bf16(sv[mt][kt][2], sv[mt][kt][3]);
        *(uint2*)&Pw[(mt * 16 + lrow) * PST + kt * 16 + lg * 4] = pk;
      }
      rs += __shfl_xor(rs, 16);
      rs += __shfl_xor(rs, 32);
      l_st[mt] += rs;
    }

    bf16x8 pa[2][2];
#pragma unroll
    for (int mt = 0; mt < 2; mt++)
#pragma unroll
      for (int ks = 0; ks < 2; ks++)
        pa[mt][ks] = *(const bf16x8*)&Pw[(mt * 16 + lrow) * PST + ks * 32 + lg * 8];
    __builtin_amdgcn_s_setprio(1);
#pragma unroll
    for (int nt = 0; nt < 5; nt++)
#pragma unroll
      for (int mt = 0; mt < 2; mt++)
#pragma unroll
        for (int ks = 0; ks < 2; ks++)
          o[mt][nt] = __builtin_amdgcn_mfma_f32_16x16x32_bf16(pa[mt][ks], vf[nt][ks], o[mt][nt], 0, 0, 0);
    __builtin_amdgcn_s_setprio(0);

    __syncthreads();
  }

#pragma unroll
  for (int mt = 0; mt < 2; mt++) {
    float rl = 1.f / l_st[mt];
    float ir[4];
#pragma unroll
    for (int r = 0; r < 4; r++) ir[r] = __shfl(rl, lg * 4 + r);
#pragma unroll
    for (int r = 0; r < 4; r++) {
      int srow = qbase_s + mt * 16 + lg * 4 + r;
#pragma unroll
      for (int nt = 0; nt < 5; nt++)
        out[(size_t)srow * DIM + h * HD + nt * 16 + lrow] = f2bf(o[mt][nt][r] * ir[r]);
    }
  }
}

extern "C" void kernel_launch(void* const* d_in, const int* in_sizes, int n_in,
                              void* d_out, int out_size, void* d_ws, size_t ws_size,
                              hipStream_t stream) {
  const float* hidden = (const float*)d_in[0];
  const float* cosb = (const float*)d_in[1];
  const float* sinb = (const float*)d_in[2];
  const float* qkv_w = (const float*)d_in[3];
  const float* qkv_b = (const float*)d_in[4];
  const float* proj_w = (const float*)d_in[5];
  const float* proj_b = (const float*)d_in[6];

  char* ws = (char*)d_ws;
  short* qkv_bf = (short*)(ws);
  short* attn_o = (short*)(ws);
  short* wp_bf = (short*)(ws + 23068672);
  short* q_bf = (short*)(ws + 125829120);
  short* k_bf = (short*)(ws + 150994944);
  short* v_tb = (short*)(ws + 176160768);
  short* h_bf = (short*)(ws + 197132288);
  short* wq_bf = (short*)(ws + 218103808);

  cast_f32_bf16<<<4096, 256, 0, stream>>>(hidden, h_bf, SEQ * DIM);
  cast_f32_bf16<<<4096, 256, 0, stream>>>(qkv_w, wq_bf, 3 * DIM * DIM);
  gemm256<<<480, 512, 0, stream>>>(h_bf, wq_bf, qkv_b, nullptr, qkv_bf, SEQ, 3 * DIM, DIM);
  rope_qk<<<20480, 256, 0, stream>>>(qkv_bf, cosb, sinb, q_bf, k_bf);
  v_transpose<<<dim3(128, 5, 16), 256, 0, stream>>>(qkv_bf, v_tb);
  cast_f32_bf16<<<2048, 256, 0, stream>>>(proj_w, wp_bf, DIM * DIM);
  attn_kernel<<<512, 512, 0, stream>>>(q_bf, k_bf, v_tb, attn_o);
  gemm_bt_bias<<<640, 256, 0, stream>>>(attn_o, wp_bf, proj_b, (float*)d_out, nullptr, SEQ, DIM, DIM);
}

// Round 20
// 308.388 us; speedup vs baseline: 1.2210x; 1.0157x over previous
//
#include <hip/hip_runtime.h>

#define SEQ 8192
#define DIM 1280
#define NHEADS 16
#define HD 80
#define HDP 96
#define NSEG 8
#define SEG 1024
#define KVB 64
#define NSTEP (SEG / KVB)
#define PST 72

typedef float f32x4 __attribute__((ext_vector_type(4)));
typedef short bf16x8 __attribute__((ext_vector_type(8)));
typedef unsigned int u32;

__device__ __forceinline__ float fast_exp2(float x) {
  return __builtin_amdgcn_exp2f(x);
}

__device__ __forceinline__ short f2bf(float f) {
  unsigned int u = __builtin_bit_cast(unsigned int, f);
  u = (u + 0x7fff + ((u >> 16) & 1)) >> 16;
  return (short)u;
}

__device__ __forceinline__ float bf2f(short s) {
  u32 u = ((u32)(unsigned short)s) << 16;
  return __builtin_bit_cast(float, u);
}

// packed f32x2 -> bf16x2 (RNE), D.lo = S0, D.hi = S1. No builtin on gfx950.
__device__ __forceinline__ u32 cvt_pk_bf16(float lo, float hi) {
  u32 r;
  asm("v_cvt_pk_bf16_f32 %0, %1, %2" : "=v"(r) : "v"(lo), "v"(hi));
  return r;
}

typedef __attribute__((address_space(1))) const unsigned int glds_src_t;
typedef __attribute__((address_space(3))) unsigned int glds_dst_t;
__device__ __forceinline__ void gload_lds16(const void* g, void* l) {
  __builtin_amdgcn_global_load_lds((glds_src_t*)g, (glds_dst_t*)l, 16, 0, 0);
}

// ---------------- generic f32 -> bf16 cast (vectorized) ----------------
__global__ void cast_f32_bf16(const float* __restrict__ in, short* __restrict__ out, int n) {
  int n4 = n >> 2;
  for (int i = blockIdx.x * blockDim.x + threadIdx.x; i < n4; i += gridDim.x * blockDim.x) {
    float4 v = ((const float4*)in)[i];
    short4 o;
    o.x = f2bf(v.x); o.y = f2bf(v.y); o.z = f2bf(v.z); o.w = f2bf(v.w);
    ((short4*)out)[i] = o;
  }
}

// ============ 256x256 bf16 GEMM, BK=64 dbuf + one-tile-deep counted vmcnt ============
// (r19-proven: stage full tile t+1, vmcnt(8) waits only tile t's loads.)
__global__ __launch_bounds__(512, 1) void gemm256(
    const short* __restrict__ A, const short* __restrict__ B,
    const float* __restrict__ bias, float* __restrict__ C,
    short* __restrict__ Cb, int M, int N, int K) {
  __shared__ short As[2][16384];  // 64 KB
  __shared__ short Bs[2][16384];  // 64 KB
  int tid = threadIdx.x;
  int w = tid >> 6, l = tid & 63;
  int lrow = l & 15, lg = l >> 4;
  int wm = w >> 2, wn = w & 3;
  int bid = blockIdx.x;
  int cpx = gridDim.x >> 3;
  int lid = (bid & 7) * cpx + (bid >> 3);
  int ntx = N >> 8;
  int m0 = (lid / ntx) * 256, n0 = (lid % ntx) * 256;

  const short* Ablk = A + (size_t)m0 * K;
  const short* Bblk = B + (size_t)n0 * K;

  f32x4 acc[8][4] = {};

#define STG_HALF(LDSB, GBASE, HALF, K0)                                       \
  {                                                                           \
    _Pragma("unroll") for (int rr = 0; rr < 2; rr++) {                        \
      int sb = rr * 512 + w * 64;                                             \
      int ss2 = sb + l;                                                       \
      int rl = ss2 >> 3, cc = ss2 & 7;                                        \
      int sl = cc ^ (rl & 7);                                                 \
      const short* sp = (GBASE) + (size_t)((HALF)*128 + rl) * K + (K0) + sl * 8; \
      gload_lds16(sp, (char*)(LDSB) + (HALF)*16384 + sb * 16);                \
    }                                                                         \
  }
#define LDA(MH, KS)                                                           \
  _Pragma("unroll") for (int mt = 0; mt < 4; mt++) {                          \
    int rowa = wm * 128 + ((MH)*4 + mt) * 16 + lrow;                          \
    int pa_ = ((KS)*4 + lg) ^ (rowa & 7);                                     \
    a[mt] = *(const bf16x8*)&As[cur][rowa * 64 + pa_ * 8];                    \
  }
#define LDB(KS)                                                               \
  _Pragma("unroll") for (int nt = 0; nt < 4; nt++) {                          \
    int rowb = wn * 64 + nt * 16 + lrow;                                      \
    int pb_ = ((KS)*4 + lg) ^ (rowb & 7);                                     \
    b[nt] = *(const bf16x8*)&Bs[cur][rowb * 64 + pb_ * 8];                    \
  }
#define MFMA16(MH)                                                            \
  _Pragma("unroll") for (int mt = 0; mt < 4; mt++)                            \
      _Pragma("unroll") for (int nt = 0; nt < 4; nt++)                        \
          acc[(MH)*4 + mt][nt] = __builtin_amdgcn_mfma_f32_16x16x32_bf16(     \
              a[mt], b[nt], acc[(MH)*4 + mt][nt], 0, 0, 0);

  {
    short* Ad = &As[0][0];
    short* Bd = &Bs[0][0];
    STG_HALF(Ad, Ablk, 0, 0);
    STG_HALF(Ad, Ablk, 1, 0);
    STG_HALF(Bd, Bblk, 0, 0);
    STG_HALF(Bd, Bblk, 1, 0);
  }
  asm volatile("s_waitcnt vmcnt(0)" ::: "memory");
  __builtin_amdgcn_s_barrier();
  asm volatile("" ::: "memory");

  int NT = K >> 6;
  for (int t = 0; t < NT; ++t) {
    int cur = t & 1;
    if (t + 1 < NT) {
      short* Ad = &As[cur ^ 1][0];
      short* Bd = &Bs[cur ^ 1][0];
      int k1 = (t + 1) << 6;
      STG_HALF(Ad, Ablk, 0, k1);
      STG_HALF(Ad, Ablk, 1, k1);
      STG_HALF(Bd, Bblk, 0, k1);
      STG_HALF(Bd, Bblk, 1, k1);
      asm volatile("s_waitcnt vmcnt(8)" ::: "memory");
    } else {
      asm volatile("s_waitcnt vmcnt(0)" ::: "memory");
    }
    __builtin_amdgcn_s_barrier();
    asm volatile("" ::: "memory");
    {
      bf16x8 a[4], b[4];
      __builtin_amdgcn_s_setprio(1);
      LDA(0, 0); LDB(0); MFMA16(0);
      LDA(1, 0); MFMA16(1);
      LDA(0, 1); LDB(1); MFMA16(0);
      LDA(1, 1); MFMA16(1);
      __builtin_amdgcn_s_setprio(0);
    }
    __builtin_amdgcn_s_barrier();
    asm volatile("" ::: "memory");
  }

  if (Cb) {
    short* E = &As[0][0];
#pragma unroll
    for (int s = 0; s < 4; s++) {
      __syncthreads();
      if (wm == (s >> 1)) {
#pragma unroll
        for (int mi = 0; mi < 4; mi++) {
          int mt2 = (s & 1) * 4 + mi;
#pragma unroll
          for (int nt = 0; nt < 4; nt++) {
            int col = wn * 64 + nt * 16 + lrow;
            float bv = bias[n0 + col];
#pragma unroll
            for (int r = 0; r < 4; r++)
              E[(mi * 16 + lg * 4 + r) * 264 + col] = f2bf(acc[mt2][nt][r] + bv);
          }
        }
      }
      __syncthreads();
#pragma unroll
      for (int j = 0; j < 4; j++) {
        int c = j * 512 + tid;
        int row = c >> 5, ch = c & 31;
        *(uint4*)&Cb[(size_t)(m0 + s * 64 + row) * N + n0 + ch * 8] =
            *(const uint4*)&E[row * 264 + ch * 8];
      }
    }
  } else {
#pragma unroll
    for (int nt = 0; nt < 4; nt++) {
      int col = n0 + wn * 64 + nt * 16 + lrow;
      float bv = bias[col];
#pragma unroll
      for (int mt = 0; mt < 8; mt++) {
        int mrow = m0 + wm * 128 + mt * 16 + lg * 4;
#pragma unroll
        for (int r = 0; r < 4; r++)
          C[(size_t)(mrow + r) * N + col] = acc[mt][nt][r] + bv;
      }
    }
  }
#undef STG_HALF
#undef LDA
#undef LDB
#undef MFMA16
}

// ---------------- 128x128 bf16 GEMM (proj; r16-proven) ----------------
__global__ __launch_bounds__(256) void gemm_bt_bias(
    const short* __restrict__ A, const short* __restrict__ B,
    const float* __restrict__ bias, float* __restrict__ C,
    short* __restrict__ Cb, int M, int N, int K) {
  __shared__ short As[2][128 * 64];
  __shared__ short Bs[2][128 * 64];
  int tid = threadIdx.x;
  int w = tid >> 6, l = tid & 63;
  int lrow = l & 15, lg = l >> 4;
  int bid = blockIdx.x;
  int cpx = gridDim.x >> 3;
  int lid = (bid & 7) * cpx + (bid >> 3);
  int ntx = N >> 7;
  int m0 = (lid / ntx) * 128, n0 = (lid % ntx) * 128;
  int wm = w & 1, wn = w >> 1;

  f32x4 acc[4][4] = {};

  const char* Abase = (const char*)A + (size_t)m0 * K * 2;
  const char* Bbase = (const char*)B + (size_t)n0 * K * 2;

#define STAGE_G(BUF, K0)                                                       \
  {                                                                            \
    _Pragma("unroll") for (int j = 0; j < 4; j++) {                            \
      int c = j * 256 + tid;                                                   \
      int row = c >> 3;                                                        \
      int slc = (c & 7) ^ (row & 7);                                           \
      size_t goff = (size_t)row * K * 2 + (size_t)(K0) * 2 + slc * 16;         \
      int loff = (j * 256 + w * 64) * 16;                                      \
      gload_lds16(Abase + goff, (char*)&As[BUF][0] + loff);                    \
      gload_lds16(Bbase + goff, (char*)&Bs[BUF][0] + loff);                    \
    }                                                                          \
  }

  STAGE_G(0, 0);
  asm volatile("s_waitcnt vmcnt(0)" ::: "memory");
  __builtin_amdgcn_s_barrier();
  asm volatile("" ::: "memory");

  for (int k0 = 0; k0 < K; k0 += 64) {
    int cur = (k0 >> 6) & 1;
    if (k0 + 64 < K) {
      STAGE_G(cur ^ 1, k0 + 64);
      asm volatile("s_waitcnt vmcnt(8)" ::: "memory");
    } else {
      asm volatile("s_waitcnt vmcnt(0)" ::: "memory");
    }
    __builtin_amdgcn_s_barrier();
    asm volatile("" ::: "memory");
#pragma unroll
    for (int kk = 0; kk < 2; kk++) {
      bf16x8 a[4], b[4];
#pragma unroll
      for (int mt = 0; mt < 4; mt++) {
        int row = wm * 64 + mt * 16 + lrow;
        int p = (kk * 4 + lg) ^ (row & 7);
        a[mt] = *(const bf16x8*)&As[cur][row * 64 + p * 8];
      }
#pragma unroll
      for (int nt = 0; nt < 4; nt++) {
        int row = wn * 64 + nt * 16 + lrow;
        int p = (kk * 4 + lg) ^ (row & 7);
        b[nt] = *(const bf16x8*)&Bs[cur][row * 64 + p * 8];
      }
#pragma unroll
      for (int mt = 0; mt < 4; mt++)
#pragma unroll
        for (int nt = 0; nt < 4; nt++)
          acc[mt][nt] = __builtin_amdgcn_mfma_f32_16x16x32_bf16(a[mt], b[nt], acc[mt][nt], 0, 0, 0);
    }
    __builtin_amdgcn_s_barrier();
    asm volatile("" ::: "memory");
  }

#pragma unroll
  for (int nt = 0; nt < 4; nt++) {
    int col = n0 + wn * 64 + nt * 16 + lrow;
    float bv = bias[col];
#pragma unroll
    for (int mt = 0; mt < 4; mt++) {
      int mrow = m0 + wm * 64 + mt * 16 + lg * 4;
      if (Cb) {
#pragma unroll
        for (int r = 0; r < 4; r++)
          Cb[(size_t)(mrow + r) * N + col] = f2bf(acc[mt][nt][r] + bv);
      } else {
#pragma unroll
        for (int r = 0; r < 4; r++)
          C[(size_t)(mrow + r) * N + col] = acc[mt][nt][r] + bv;
      }
    }
  }
}

// ---------------- RoPE for q,k (bf16 in, bf16 out, head-major, pad to 96) ----------------
__global__ void rope_qk(const short* __restrict__ qkv, const float* __restrict__ cosb,
                        const float* __restrict__ sinb, short* __restrict__ qg,
                        short* __restrict__ kg) {
  int t = blockIdx.x * blockDim.x + threadIdx.x;
  if (t >= SEQ * NHEADS * 40) return;
  int d = t % 40;
  int h = (t / 40) & 15;
  int s = t / 640;
  const short* row = qkv + (size_t)s * (3 * DIM);
  float c0 = cosb[s * HD + d], c1 = cosb[s * HD + d + 40];
  float s0 = sinb[s * HD + d], s1 = sinb[s * HD + d + 40];
  float x1 = bf2f(row[h * HD + d]), x2 = bf2f(row[h * HD + d + 40]);
  float q0 = x1 * c0 - x2 * s0;
  float q1 = x2 * c1 + x1 * s1;
  float y1 = bf2f(row[DIM + h * HD + d]), y2 = bf2f(row[DIM + h * HD + d + 40]);
  float k0 = y1 * c0 - y2 * s0;
  float k1 = y2 * c1 + y1 * s1;
  const float sc = 0.11180339887498949f * 1.4426950408889634f;
  size_t base = ((size_t)h * SEQ + s) * HDP;
  qg[base + d] = f2bf(q0 * sc);
  qg[base + d + 40] = f2bf(q1 * sc);
  kg[base + d] = f2bf(k0);
  kg[base + d + 40] = f2bf(k1);
  if (d < 16) { qg[base + 80 + d] = 0; kg[base + 80 + d] = 0; }
}

// ---------------- V transpose: qkv bf16 (S,3,H,80) -> vt bf16 (H,80,S) ----------------
__global__ void v_transpose(const short* __restrict__ qkv, short* __restrict__ vt) {
  __shared__ short T[16][72];
  int st = blockIdx.x, dt = blockIdx.y, h = blockIdx.z;
  int d0 = dt * 16, s0 = st * 64;
  int t = threadIdx.x;
  int dd = t & 15, ss = t >> 4;
#pragma unroll
  for (int j = 0; j < 4; j++) {
    int s = ss + j * 16;
    T[dd][s] = qkv[(size_t)(s0 + s) * (3 * DIM) + 2 * DIM + h * HD + d0 + dd];
  }
  __syncthreads();
  int s2 = t & 63, dr = t >> 6;
#pragma unroll
  for (int j = 0; j < 4; j++) {
    int d = dr + j * 4;
    vt[((size_t)(h * HD + d0 + d)) * SEQ + s0 + s2] = T[d][s2];
  }
}

// ---------------- flash attention v8: 4 waves/block, 2 blocks/CU ----------------
// Same per-wave math as v7 (32 q-rows, K-LDS dbuf coop staging, swapped QK,
// cvt_pk P-pack, setprio, batched V after QK). AGPR accounting (~224 regs/
// wave incl acc) showed v7's 8-wave block could only fit 1 block/CU ->
// lockstep barrier, no cross-block overlap, Occupancy 22%. 4-wave blocks
// (LDS 50 KB, 2 waves/SIMD x 224 = 448 <= 512) give 2 co-resident blocks:
// when one block barriers, the other's waves issue MFMA (m114 overlap).
__global__ __launch_bounds__(256, 2) void attn_kernel(
    const short* __restrict__ qg, const short* __restrict__ kg,
    const short* __restrict__ vt, short* __restrict__ out) {
  __shared__ short Ks[2][64 * 128];  // 32 KB
  __shared__ short Pl[4][32 * PST];  // 18 KB
  int bid = blockIdx.x;
  int b = bid & 7, h = (bid >> 3) & 15, qt = bid >> 7;  // qt in 0..7
  int tid = threadIdx.x;
  int w = tid >> 6, l = tid & 63;
  int lrow = l & 15, lg = l >> 4;
  int qbase_s = b * SEG + qt * 128 + w * 32;

  const short* qh = qg + (size_t)h * SEQ * HDP;
  const short* kh = kg + (size_t)h * SEQ * HDP;
  const short* vh = vt + (size_t)h * HD * SEQ;

  // K stage: 1024 slots x 16B, 4 rounds of 256 threads.
#define STAGE_K(BUF, KEY0N)                                                    \
  {                                                                            \
    _Pragma("unroll") for (int sr = 0; sr < 4; sr++) {                         \
      int sbase = sr * 256 + w * 64;                                           \
      int ss = sbase + l;                                                      \
      int skey = ss >> 4, sc = ss & 15;                                        \
      int slc = sc ^ (skey & 7);                                               \
      const short* ssrc =                                                      \
          kh + (size_t)((KEY0N) + skey) * HDP + (slc < 12 ? slc * 8 : 0);      \
      gload_lds16(ssrc, (char*)&Ks[BUF][0] + sbase * 16);                      \
    }                                                                          \
  }

  bf16x8 qf[2][3];
#pragma unroll
  for (int mt = 0; mt < 2; mt++)
#pragma unroll
    for (int ks = 0; ks < 3; ks++)
      qf[mt][ks] = *(const bf16x8*)&qh[(size_t)(qbase_s + mt * 16 + lrow) * HDP + ks * 32 + lg * 8];

  f32x4 o[2][5] = {};
  float m_st[2] = {-1e30f, -1e30f};
  float l_st[2] = {0.f, 0.f};

  short* Pw = &Pl[w][0];

  STAGE_K(0, b * SEG);
  __syncthreads();

  for (int i = 0; i < NSTEP; i++) {
    int cur = i & 1;
    int key0 = b * SEG + i * KVB;
    if (i + 1 < NSTEP) {
      STAGE_K(cur ^ 1, key0 + KVB);
    }

    f32x4 sv[2][4] = {};
    __builtin_amdgcn_s_setprio(1);
#pragma unroll
    for (int kt = 0; kt < 4; kt++) {
      bf16x8 kf[3];
      int key = kt * 16 + lrow;
#pragma unroll
      for (int ks = 0; ks < 3; ks++) {
        int p = (ks * 4 + lg) ^ (key & 7);
        kf[ks] = *(const bf16x8*)&Ks[cur][key * 128 + p * 8];
      }
#pragma unroll
      for (int mt = 0; mt < 2; mt++)
#pragma unroll
        for (int ks = 0; ks < 3; ks++)
          sv[mt][kt] = __builtin_amdgcn_mfma_f32_16x16x32_bf16(kf[ks], qf[mt][ks], sv[mt][kt], 0, 0, 0);
    }
    __builtin_amdgcn_s_setprio(0);

    bf16x8 vf[5][2];
#pragma unroll
    for (int nt = 0; nt < 5; nt++)
#pragma unroll
      for (int ks = 0; ks < 2; ks++)
        vf[nt][ks] = *(const bf16x8*)&vh[(size_t)(nt * 16 + lrow) * SEQ + key0 + ks * 32 + lg * 8];

    float cm[2];
#pragma unroll
    for (int mt = 0; mt < 2; mt++) {
      float a0 = fmaxf(fmaxf(sv[mt][0][0], sv[mt][0][1]), fmaxf(sv[mt][0][2], sv[mt][0][3]));
      float a1 = fmaxf(fmaxf(sv[mt][1][0], sv[mt][1][1]), fmaxf(sv[mt][1][2], sv[mt][1][3]));
      float a2 = fmaxf(fmaxf(sv[mt][2][0], sv[mt][2][1]), fmaxf(sv[mt][2][2], sv[mt][2][3]));
      float a3 = fmaxf(fmaxf(sv[mt][3][0], sv[mt][3][1]), fmaxf(sv[mt][3][2], sv[mt][3][3]));
      float c = fmaxf(fmaxf(a0, a1), fmaxf(a2, a3));
      c = fmaxf(c, __shfl_xor(c, 16));
      c = fmaxf(c, __shfl_xor(c, 32));
      cm[mt] = c;
    }
    if (__any((cm[0] > m_st[0] + 8.f) || (cm[1] > m_st[1] + 8.f))) {
#pragma unroll
      for (int mt = 0; mt < 2; mt++) {
        float mn = fmaxf(m_st[mt], cm[mt]);
        float c = fast_exp2(m_st[mt] - mn);
        m_st[mt] = mn;
        l_st[mt] *= c;
        float cr[4];
#pragma unroll
        for (int r = 0; r < 4; r++) cr[r] = __shfl(c, lg * 4 + r);
#pragma unroll
        for (int nt = 0; nt < 5; nt++)
#pragma unroll
          for (int r = 0; r < 4; r++) o[mt][nt][r] *= cr[r];
      }
    }
#pragma unroll
    for (int mt = 0; mt < 2; mt++) {
      float rs = 0.f;
#pragma unroll
      for (int kt = 0; kt < 4; kt++) {
#pragma unroll
        for (int r = 0; r < 4; r++) {
          sv[mt][kt][r] = fast_exp2(sv[mt][kt][r] - m_st[mt]);
          rs += sv[mt][kt][r];
        }
        uint2 pk;
        pk.x = cvt_pk_bf16(sv[mt][kt][0], sv[mt][kt][1]);
        pk.y = cvt_pk_bf16(sv[mt][kt][2], sv[mt][kt][3]);
        *(uint2*)&Pw[(mt * 16 + lrow) * PST + kt * 16 + lg * 4] = pk;
      }
      rs += __shfl_xor(rs, 16);
      rs += __shfl_xor(rs, 32);
      l_st[mt] += rs;
    }

    bf16x8 pa[2][2];
#pragma unroll
    for (int mt = 0; mt < 2; mt++)
#pragma unroll
      for (int ks = 0; ks < 2; ks++)
        pa[mt][ks] = *(const bf16x8*)&Pw[(mt * 16 + lrow) * PST + ks * 32 + lg * 8];
    __builtin_amdgcn_s_setprio(1);
#pragma unroll
    for (int nt = 0; nt < 5; nt++)
#pragma unroll
      for (int mt = 0; mt < 2; mt++)
#pragma unroll
        for (int ks = 0; ks < 2; ks++)
          o[mt][nt] = __builtin_amdgcn_mfma_f32_16x16x32_bf16(pa[mt][ks], vf[nt][ks], o[mt][nt], 0, 0, 0);
    __builtin_amdgcn_s_setprio(0);

    __syncthreads();
  }

#pragma unroll
  for (int mt = 0; mt < 2; mt++) {
    float rl = 1.f / l_st[mt];
    float ir[4];
#pragma unroll
    for (int r = 0; r < 4; r++) ir[r] = __shfl(rl, lg * 4 + r);
#pragma unroll
    for (int r = 0; r < 4; r++) {
      int srow = qbase_s + mt * 16 + lg * 4 + r;
#pragma unroll
      for (int nt = 0; nt < 5; nt++)
        out[(size_t)srow * DIM + h * HD + nt * 16 + lrow] = f2bf(o[mt][nt][r] * ir[r]);
    }
  }
}

extern "C" void kernel_launch(void* const* d_in, const int* in_sizes, int n_in,
                              void* d_out, int out_size, void* d_ws, size_t ws_size,
                              hipStream_t stream) {
  const float* hidden = (const float*)d_in[0];
  const float* cosb = (const float*)d_in[1];
  const float* sinb = (const float*)d_in[2];
  const float* qkv_w = (const float*)d_in[3];
  const float* qkv_b = (const float*)d_in[4];
  const float* proj_w = (const float*)d_in[5];
  const float* proj_b = (const float*)d_in[6];

  char* ws = (char*)d_ws;
  short* qkv_bf = (short*)(ws);
  short* attn_o = (short*)(ws);
  short* wp_bf = (short*)(ws + 23068672);
  short* q_bf = (short*)(ws + 125829120);
  short* k_bf = (short*)(ws + 150994944);
  short* v_tb = (short*)(ws + 176160768);
  short* h_bf = (short*)(ws + 197132288);
  short* wq_bf = (short*)(ws + 218103808);

  cast_f32_bf16<<<4096, 256, 0, stream>>>(hidden, h_bf, SEQ * DIM);
  cast_f32_bf16<<<4096, 256, 0, stream>>>(qkv_w, wq_bf, 3 * DIM * DIM);
  gemm256<<<480, 512, 0, stream>>>(h_bf, wq_bf, qkv_b, nullptr, qkv_bf, SEQ, 3 * DIM, DIM);
  rope_qk<<<20480, 256, 0, stream>>>(qkv_bf, cosb, sinb, q_bf, k_bf);
  v_transpose<<<dim3(128, 5, 16), 256, 0, stream>>>(qkv_bf, v_tb);
  cast_f32_bf16<<<2048, 256, 0, stream>>>(proj_w, wp_bf, DIM * DIM);
  attn_kernel<<<1024, 256, 0, stream>>>(q_bf, k_bf, v_tb, attn_o);
  gemm_bt_bias<<<640, 256, 0, stream>>>(attn_o, wp_bf, proj_b, (float*)d_out, nullptr, SEQ, DIM, DIM);
}

// Round 21
// 301.303 us; speedup vs baseline: 1.2497x; 1.0235x over previous
//
#include <hip/hip_runtime.h>

#define SEQ 8192
#define DIM 1280
#define NHEADS 16
#define HD 80
#define HDP 96
#define NSEG 8
#define SEG 1024
#define KVB 64
#define NSTEP (SEG / KVB)
#define PST 72

typedef float f32x4 __attribute__((ext_vector_type(4)));
typedef short bf16x8 __attribute__((ext_vector_type(8)));
typedef unsigned int u32;

__device__ __forceinline__ float fast_exp2(float x) {
  return __builtin_amdgcn_exp2f(x);
}

__device__ __forceinline__ short f2bf(float f) {
  unsigned int u = __builtin_bit_cast(unsigned int, f);
  u = (u + 0x7fff + ((u >> 16) & 1)) >> 16;
  return (short)u;
}

__device__ __forceinline__ float bf2f(short s) {
  u32 u = ((u32)(unsigned short)s) << 16;
  return __builtin_bit_cast(float, u);
}

// packed f32x2 -> bf16x2 (RNE), D.lo = S0, D.hi = S1. No builtin on gfx950.
__device__ __forceinline__ u32 cvt_pk_bf16(float lo, float hi) {
  u32 r;
  asm("v_cvt_pk_bf16_f32 %0, %1, %2" : "=v"(r) : "v"(lo), "v"(hi));
  return r;
}

typedef __attribute__((address_space(1))) const unsigned int glds_src_t;
typedef __attribute__((address_space(3))) unsigned int glds_dst_t;
__device__ __forceinline__ void gload_lds16(const void* g, void* l) {
  __builtin_amdgcn_global_load_lds((glds_src_t*)g, (glds_dst_t*)l, 16, 0, 0);
}

// ---------------- generic f32 -> bf16 cast (vectorized) ----------------
__global__ void cast_f32_bf16(const float* __restrict__ in, short* __restrict__ out, int n) {
  int n4 = n >> 2;
  for (int i = blockIdx.x * blockDim.x + threadIdx.x; i < n4; i += gridDim.x * blockDim.x) {
    float4 v = ((const float4*)in)[i];
    short4 o;
    o.x = f2bf(v.x); o.y = f2bf(v.y); o.z = f2bf(v.z); o.w = f2bf(v.w);
    ((short4*)out)[i] = o;
  }
}

// ====== 256x256 bf16 GEMM, BK=32 dbuf, 64 KB LDS -> 2 blocks/CU ======
// r20 (BK=64 dbuf, 128 KB LDS) was capped at 1 block/CU: 8 lockstep waves,
// no cross-block overlap for the 2 barrier drains/tile, plus a 256+224
// dispatch tail (480 blocks, 1 slot/CU). BK=32 halves LDS -> 2 blocks/CU:
// the co-resident block's MFMA covers this block's barrier/stage drains
// (m114 mechanism, same fix that worked for attn in r20), and all 480
// blocks run in one dispatch round. One-tile-deep counted vmcnt kept
// (vmcnt(4) waits tile t's 4 loads: one full tile + other-block cover).
// Swizzle: chunk p = lg ^ ((row>>1)&3) -> 2-way max (free); same involution
// on the stage-side global source (linear LDS dest, rule 21).
// Single 64 KB arena: A bufs = shorts [0,16384), B bufs = [16384,32768);
// epilogue (64x264 = 16.9K shorts) reuses the whole arena safely.
__global__ __launch_bounds__(512, 2) void gemm256(
    const short* __restrict__ A, const short* __restrict__ B,
    const float* __restrict__ bias, float* __restrict__ C,
    short* __restrict__ Cb, int M, int N, int K) {
  __shared__ short Sh[32768];  // 64 KB
  int tid = threadIdx.x;
  int w = tid >> 6, l = tid & 63;
  int lrow = l & 15, lg = l >> 4;
  int wm = w >> 2, wn = w & 3;
  int bid = blockIdx.x;
  int cpx = gridDim.x >> 3;
  int lid = (bid & 7) * cpx + (bid >> 3);
  int ntx = N >> 8;
  int m0 = (lid / ntx) * 256, n0 = (lid % ntx) * 256;

  const short* Ablk = A + (size_t)m0 * K;
  const short* Bblk = B + (size_t)n0 * K;

  f32x4 acc[8][4] = {};

// stage one 256x32 operand tile: 1024 slots x 16B, 2 rounds of 512 thr.
// OPB: 0 = A region (byte 0), 1 = B region (byte 32768).
#define STG32(BUF, OPB, GBASE, K0)                                            \
  {                                                                           \
    _Pragma("unroll") for (int rr = 0; rr < 2; rr++) {                        \
      int sb = rr * 512 + w * 64;                                             \
      int ss2 = sb + l;                                                       \
      int rl = ss2 >> 2, cc = ss2 & 3;                                        \
      int sl = cc ^ ((rl >> 1) & 3);                                          \
      const short* sp = (GBASE) + (size_t)rl * K + (K0) + sl * 8;             \
      gload_lds16(sp, (char*)Sh + (OPB)*32768 + (BUF)*16384 + sb * 16);       \
    }                                                                         \
  }
#define LDA32(MH)                                                             \
  _Pragma("unroll") for (int mt = 0; mt < 4; mt++) {                          \
    int rowa = wm * 128 + ((MH)*4 + mt) * 16 + lrow;                          \
    int pa_ = lg ^ ((rowa >> 1) & 3);                                         \
    a[mt] = *(const bf16x8*)&Sh[cur * 8192 + rowa * 32 + pa_ * 8];            \
  }
#define LDB32()                                                               \
  _Pragma("unroll") for (int nt = 0; nt < 4; nt++) {                          \
    int rowb = wn * 64 + nt * 16 + lrow;                                      \
    int pb_ = lg ^ ((rowb >> 1) & 3);                                         \
    b[nt] = *(const bf16x8*)&Sh[16384 + cur * 8192 + rowb * 32 + pb_ * 8];    \
  }
#define MFMA16X(MH)                                                           \
  _Pragma("unroll") for (int mt = 0; mt < 4; mt++)                            \
      _Pragma("unroll") for (int nt = 0; nt < 4; nt++)                        \
          acc[(MH)*4 + mt][nt] = __builtin_amdgcn_mfma_f32_16x16x32_bf16(     \
              a[mt], b[nt], acc[(MH)*4 + mt][nt], 0, 0, 0);

  STG32(0, 0, Ablk, 0);
  STG32(0, 1, Bblk, 0);
  asm volatile("s_waitcnt vmcnt(0)" ::: "memory");
  __builtin_amdgcn_s_barrier();
  asm volatile("" ::: "memory");

  int NT = K >> 5;
  for (int t = 0; t < NT; ++t) {
    int cur = t & 1;
    if (t + 1 < NT) {
      int k1 = (t + 1) << 5;
      STG32(cur ^ 1, 0, Ablk, k1);
      STG32(cur ^ 1, 1, Bblk, k1);
      asm volatile("s_waitcnt vmcnt(4)" ::: "memory");
    } else {
      asm volatile("s_waitcnt vmcnt(0)" ::: "memory");
    }
    __builtin_amdgcn_s_barrier();  // buf[cur] fully populated across waves
    asm volatile("" ::: "memory");
    {
      bf16x8 a[4], b[4];
      __builtin_amdgcn_s_setprio(1);
      LDA32(0); LDB32(); MFMA16X(0);
      LDA32(1); MFMA16X(1);
      __builtin_amdgcn_s_setprio(0);
    }
    __builtin_amdgcn_s_barrier();  // all reads of buf[cur] done
    asm volatile("" ::: "memory");
  }

  if (Cb) {
    // LDS-staged bf16 epilogue: 4 sweeps of 64 rows x 256 cols, stride 264
    // shorts, full 512B row stores (ideal HBM sectors).
#pragma unroll
    for (int s = 0; s < 4; s++) {
      __syncthreads();
      if (wm == (s >> 1)) {
#pragma unroll
        for (int mi = 0; mi < 4; mi++) {
          int mt2 = (s & 1) * 4 + mi;
#pragma unroll
          for (int nt = 0; nt < 4; nt++) {
            int col = wn * 64 + nt * 16 + lrow;
            float bv = bias[n0 + col];
#pragma unroll
            for (int r = 0; r < 4; r++)
              Sh[(mi * 16 + lg * 4 + r) * 264 + col] = f2bf(acc[mt2][nt][r] + bv);
          }
        }
      }
      __syncthreads();
#pragma unroll
      for (int j = 0; j < 4; j++) {
        int c = j * 512 + tid;
        int row = c >> 5, ch = c & 31;
        *(uint4*)&Cb[(size_t)(m0 + s * 64 + row) * N + n0 + ch * 8] =
            *(const uint4*)&Sh[row * 264 + ch * 8];
      }
    }
  } else {
#pragma unroll
    for (int nt = 0; nt < 4; nt++) {
      int col = n0 + wn * 64 + nt * 16 + lrow;
      float bv = bias[col];
#pragma unroll
      for (int mt = 0; mt < 8; mt++) {
        int mrow = m0 + wm * 128 + mt * 16 + lg * 4;
#pragma unroll
        for (int r = 0; r < 4; r++)
          C[(size_t)(mrow + r) * N + col] = acc[mt][nt][r] + bv;
      }
    }
  }
#undef STG32
#undef LDA32
#undef LDB32
#undef MFMA16X
}

// ---------------- 128x128 bf16 GEMM (proj; r16-proven) ----------------
__global__ __launch_bounds__(256) void gemm_bt_bias(
    const short* __restrict__ A, const short* __restrict__ B,
    const float* __restrict__ bias, float* __restrict__ C,
    short* __restrict__ Cb, int M, int N, int K) {
  __shared__ short As[2][128 * 64];
  __shared__ short Bs[2][128 * 64];
  int tid = threadIdx.x;
  int w = tid >> 6, l = tid & 63;
  int lrow = l & 15, lg = l >> 4;
  int bid = blockIdx.x;
  int cpx = gridDim.x >> 3;
  int lid = (bid & 7) * cpx + (bid >> 3);
  int ntx = N >> 7;
  int m0 = (lid / ntx) * 128, n0 = (lid % ntx) * 128;
  int wm = w & 1, wn = w >> 1;

  f32x4 acc[4][4] = {};

  const char* Abase = (const char*)A + (size_t)m0 * K * 2;
  const char* Bbase = (const char*)B + (size_t)n0 * K * 2;

#define STAGE_G(BUF, K0)                                                       \
  {                                                                            \
    _Pragma("unroll") for (int j = 0; j < 4; j++) {                            \
      int c = j * 256 + tid;                                                   \
      int row = c >> 3;                                                        \
      int slc = (c & 7) ^ (row & 7);                                           \
      size_t goff = (size_t)row * K * 2 + (size_t)(K0) * 2 + slc * 16;         \
      int loff = (j * 256 + w * 64) * 16;                                      \
      gload_lds16(Abase + goff, (char*)&As[BUF][0] + loff);                    \
      gload_lds16(Bbase + goff, (char*)&Bs[BUF][0] + loff);                    \
    }                                                                          \
  }

  STAGE_G(0, 0);
  asm volatile("s_waitcnt vmcnt(0)" ::: "memory");
  __builtin_amdgcn_s_barrier();
  asm volatile("" ::: "memory");

  for (int k0 = 0; k0 < K; k0 += 64) {
    int cur = (k0 >> 6) & 1;
    if (k0 + 64 < K) {
      STAGE_G(cur ^ 1, k0 + 64);
      asm volatile("s_waitcnt vmcnt(8)" ::: "memory");
    } else {
      asm volatile("s_waitcnt vmcnt(0)" ::: "memory");
    }
    __builtin_amdgcn_s_barrier();
    asm volatile("" ::: "memory");
#pragma unroll
    for (int kk = 0; kk < 2; kk++) {
      bf16x8 a[4], b[4];
#pragma unroll
      for (int mt = 0; mt < 4; mt++) {
        int row = wm * 64 + mt * 16 + lrow;
        int p = (kk * 4 + lg) ^ (row & 7);
        a[mt] = *(const bf16x8*)&As[cur][row * 64 + p * 8];
      }
#pragma unroll
      for (int nt = 0; nt < 4; nt++) {
        int row = wn * 64 + nt * 16 + lrow;
        int p = (kk * 4 + lg) ^ (row & 7);
        b[nt] = *(const bf16x8*)&Bs[cur][row * 64 + p * 8];
      }
#pragma unroll
      for (int mt = 0; mt < 4; mt++)
#pragma unroll
        for (int nt = 0; nt < 4; nt++)
          acc[mt][nt] = __builtin_amdgcn_mfma_f32_16x16x32_bf16(a[mt], b[nt], acc[mt][nt], 0, 0, 0);
    }
    __builtin_amdgcn_s_barrier();
    asm volatile("" ::: "memory");
  }

#pragma unroll
  for (int nt = 0; nt < 4; nt++) {
    int col = n0 + wn * 64 + nt * 16 + lrow;
    float bv = bias[col];
#pragma unroll
    for (int mt = 0; mt < 4; mt++) {
      int mrow = m0 + wm * 64 + mt * 16 + lg * 4;
      if (Cb) {
#pragma unroll
        for (int r = 0; r < 4; r++)
          Cb[(size_t)(mrow + r) * N + col] = f2bf(acc[mt][nt][r] + bv);
      } else {
#pragma unroll
        for (int r = 0; r < 4; r++)
          C[(size_t)(mrow + r) * N + col] = acc[mt][nt][r] + bv;
      }
    }
  }
}

// ---------------- RoPE for q,k (bf16 in, bf16 out, head-major, pad to 96) ----------------
__global__ void rope_qk(const short* __restrict__ qkv, const float* __restrict__ cosb,
                        const float* __restrict__ sinb, short* __restrict__ qg,
                        short* __restrict__ kg) {
  int t = blockIdx.x * blockDim.x + threadIdx.x;
  if (t >= SEQ * NHEADS * 40) return;
  int d = t % 40;
  int h = (t / 40) & 15;
  int s = t / 640;
  const short* row = qkv + (size_t)s * (3 * DIM);
  float c0 = cosb[s * HD + d], c1 = cosb[s * HD + d + 40];
  float s0 = sinb[s * HD + d], s1 = sinb[s * HD + d + 40];
  float x1 = bf2f(row[h * HD + d]), x2 = bf2f(row[h * HD + d + 40]);
  float q0 = x1 * c0 - x2 * s0;
  float q1 = x2 * c1 + x1 * s1;
  float y1 = bf2f(row[DIM + h * HD + d]), y2 = bf2f(row[DIM + h * HD + d + 40]);
  float k0 = y1 * c0 - y2 * s0;
  float k1 = y2 * c1 + y1 * s1;
  const float sc = 0.11180339887498949f * 1.4426950408889634f;
  size_t base = ((size_t)h * SEQ + s) * HDP;
  qg[base + d] = f2bf(q0 * sc);
  qg[base + d + 40] = f2bf(q1 * sc);
  kg[base + d] = f2bf(k0);
  kg[base + d + 40] = f2bf(k1);
  if (d < 16) { qg[base + 80 + d] = 0; kg[base + 80 + d] = 0; }
}

// ---------------- V transpose: qkv bf16 (S,3,H,80) -> vt bf16 (H,80,S) ----------------
__global__ void v_transpose(const short* __restrict__ qkv, short* __restrict__ vt) {
  __shared__ short T[16][72];
  int st = blockIdx.x, dt = blockIdx.y, h = blockIdx.z;
  int d0 = dt * 16, s0 = st * 64;
  int t = threadIdx.x;
  int dd = t & 15, ss = t >> 4;
#pragma unroll
  for (int j = 0; j < 4; j++) {
    int s = ss + j * 16;
    T[dd][s] = qkv[(size_t)(s0 + s) * (3 * DIM) + 2 * DIM + h * HD + d0 + dd];
  }
  __syncthreads();
  int s2 = t & 63, dr = t >> 6;
#pragma unroll
  for (int j = 0; j < 4; j++) {
    int d = dr + j * 4;
    vt[((size_t)(h * HD + d0 + d)) * SEQ + s0 + s2] = T[d][s2];
  }
}

// ---------------- flash attention v8 (r20-proven: 4 waves, 2 blocks/CU) ----------------
__global__ __launch_bounds__(256, 2) void attn_kernel(
    const short* __restrict__ qg, const short* __restrict__ kg,
    const short* __restrict__ vt, short* __restrict__ out) {
  __shared__ short Ks[2][64 * 128];  // 32 KB
  __shared__ short Pl[4][32 * PST];  // 18 KB
  int bid = blockIdx.x;
  int b = bid & 7, h = (bid >> 3) & 15, qt = bid >> 7;
  int tid = threadIdx.x;
  int w = tid >> 6, l = tid & 63;
  int lrow = l & 15, lg = l >> 4;
  int qbase_s = b * SEG + qt * 128 + w * 32;

  const short* qh = qg + (size_t)h * SEQ * HDP;
  const short* kh = kg + (size_t)h * SEQ * HDP;
  const short* vh = vt + (size_t)h * HD * SEQ;

#define STAGE_K(BUF, KEY0N)                                                    \
  {                                                                            \
    _Pragma("unroll") for (int sr = 0; sr < 4; sr++) {                         \
      int sbase = sr * 256 + w * 64;                                           \
      int ss = sbase + l;                                                      \
      int skey = ss >> 4, sc = ss & 15;                                        \
      int slc = sc ^ (skey & 7);                                               \
      const short* ssrc =                                                      \
          kh + (size_t)((KEY0N) + skey) * HDP + (slc < 12 ? slc * 8 : 0);      \
      gload_lds16(ssrc, (char*)&Ks[BUF][0] + sbase * 16);                      \
    }                                                                          \
  }

  bf16x8 qf[2][3];
#pragma unroll
  for (int mt = 0; mt < 2; mt++)
#pragma unroll
    for (int ks = 0; ks < 3; ks++)
      qf[mt][ks] = *(const bf16x8*)&qh[(size_t)(qbase_s + mt * 16 + lrow) * HDP + ks * 32 + lg * 8];

  f32x4 o[2][5] = {};
  float m_st[2] = {-1e30f, -1e30f};
  float l_st[2] = {0.f, 0.f};

  short* Pw = &Pl[w][0];

  STAGE_K(0, b * SEG);
  __syncthreads();

  for (int i = 0; i < NSTEP; i++) {
    int cur = i & 1;
    int key0 = b * SEG + i * KVB;
    if (i + 1 < NSTEP) {
      STAGE_K(cur ^ 1, key0 + KVB);
    }

    f32x4 sv[2][4] = {};
    __builtin_amdgcn_s_setprio(1);
#pragma unroll
    for (int kt = 0; kt < 4; kt++) {
      bf16x8 kf[3];
      int key = kt * 16 + lrow;
#pragma unroll
      for (int ks = 0; ks < 3; ks++) {
        int p = (ks * 4 + lg) ^ (key & 7);
        kf[ks] = *(const bf16x8*)&Ks[cur][key * 128 + p * 8];
      }
#pragma unroll
      for (int mt = 0; mt < 2; mt++)
#pragma unroll
        for (int ks = 0; ks < 3; ks++)
          sv[mt][kt] = __builtin_amdgcn_mfma_f32_16x16x32_bf16(kf[ks], qf[mt][ks], sv[mt][kt], 0, 0, 0);
    }
    __builtin_amdgcn_s_setprio(0);

    bf16x8 vf[5][2];
#pragma unroll
    for (int nt = 0; nt < 5; nt++)
#pragma unroll
      for (int ks = 0; ks < 2; ks++)
        vf[nt][ks] = *(const bf16x8*)&vh[(size_t)(nt * 16 + lrow) * SEQ + key0 + ks * 32 + lg * 8];

    float cm[2];
#pragma unroll
    for (int mt = 0; mt < 2; mt++) {
      float a0 = fmaxf(fmaxf(sv[mt][0][0], sv[mt][0][1]), fmaxf(sv[mt][0][2], sv[mt][0][3]));
      float a1 = fmaxf(fmaxf(sv[mt][1][0], sv[mt][1][1]), fmaxf(sv[mt][1][2], sv[mt][1][3]));
      float a2 = fmaxf(fmaxf(sv[mt][2][0], sv[mt][2][1]), fmaxf(sv[mt][2][2], sv[mt][2][3]));
      float a3 = fmaxf(fmaxf(sv[mt][3][0], sv[mt][3][1]), fmaxf(sv[mt][3][2], sv[mt][3][3]));
      float c = fmaxf(fmaxf(a0, a1), fmaxf(a2, a3));
      c = fmaxf(c, __shfl_xor(c, 16));
      c = fmaxf(c, __shfl_xor(c, 32));
      cm[mt] = c;
    }
    if (__any((cm[0] > m_st[0] + 8.f) || (cm[1] > m_st[1] + 8.f))) {
#pragma unroll
      for (int mt = 0; mt < 2; mt++) {
        float mn = fmaxf(m_st[mt], cm[mt]);
        float c = fast_exp2(m_st[mt] - mn);
        m_st[mt] = mn;
        l_st[mt] *= c;
        float cr[4];
#pragma unroll
        for (int r = 0; r < 4; r++) cr[r] = __shfl(c, lg * 4 + r);
#pragma unroll
        for (int nt = 0; nt < 5; nt++)
#pragma unroll
          for (int r = 0; r < 4; r++) o[mt][nt][r] *= cr[r];
      }
    }
#pragma unroll
    for (int mt = 0; mt < 2; mt++) {
      float rs = 0.f;
#pragma unroll
      for (int kt = 0; kt < 4; kt++) {
#pragma unroll
        for (int r = 0; r < 4; r++) {
          sv[mt][kt][r] = fast_exp2(sv[mt][kt][r] - m_st[mt]);
          rs += sv[mt][kt][r];
        }
        uint2 pk;
        pk.x = cvt_pk_bf16(sv[mt][kt][0], sv[mt][kt][1]);
        pk.y = cvt_pk_bf16(sv[mt][kt][2], sv[mt][kt][3]);
        *(uint2*)&Pw[(mt * 16 + lrow) * PST + kt * 16 + lg * 4] = pk;
      }
      rs += __shfl_xor(rs, 16);
      rs += __shfl_xor(rs, 32);
      l_st[mt] += rs;
    }

    bf16x8 pa[2][2];
#pragma unroll
    for (int mt = 0; mt < 2; mt++)
#pragma unroll
      for (int ks = 0; ks < 2; ks++)
        pa[mt][ks] = *(const bf16x8*)&Pw[(mt * 16 + lrow) * PST + ks * 32 + lg * 8];
    __builtin_amdgcn_s_setprio(1);
#pragma unroll
    for (int nt = 0; nt < 5; nt++)
#pragma unroll
      for (int mt = 0; mt < 2; mt++)
#pragma unroll
        for (int ks = 0; ks < 2; ks++)
          o[mt][nt] = __builtin_amdgcn_mfma_f32_16x16x32_bf16(pa[mt][ks], vf[nt][ks], o[mt][nt], 0, 0, 0);
    __builtin_amdgcn_s_setprio(0);

    __syncthreads();
  }

#pragma unroll
  for (int mt = 0; mt < 2; mt++) {
    float rl = 1.f / l_st[mt];
    float ir[4];
#pragma unroll
    for (int r = 0; r < 4; r++) ir[r] = __shfl(rl, lg * 4 + r);
#pragma unroll
    for (int r = 0; r < 4; r++) {
      int srow = qbase_s + mt * 16 + lg * 4 + r;
#pragma unroll
      for (int nt = 0; nt < 5; nt++)
        out[(size_t)srow * DIM + h * HD + nt * 16 + lrow] = f2bf(o[mt][nt][r] * ir[r]);
    }
  }
}

extern "C" void kernel_launch(void* const* d_in, const int* in_sizes, int n_in,
                              void* d_out, int out_size, void* d_ws, size_t ws_size,
                              hipStream_t stream) {
  const float* hidden = (const float*)d_in[0];
  const float* cosb = (const float*)d_in[1];
  const float* sinb = (const float*)d_in[2];
  const float* qkv_w = (const float*)d_in[3];
  const float* qkv_b = (const float*)d_in[4];
  const float* proj_w = (const float*)d_in[5];
  const float* proj_b = (const float*)d_in[6];

  char* ws = (char*)d_ws;
  short* qkv_bf = (short*)(ws);
  short* attn_o = (short*)(ws);
  short* wp_bf = (short*)(ws + 23068672);
  short* q_bf = (short*)(ws + 125829120);
  short* k_bf = (short*)(ws + 150994944);
  short* v_tb = (short*)(ws + 176160768);
  short* h_bf = (short*)(ws + 197132288);
  short* wq_bf = (short*)(ws + 218103808);

  cast_f32_bf16<<<4096, 256, 0, stream>>>(hidden, h_bf, SEQ * DIM);
  cast_f32_bf16<<<4096, 256, 0, stream>>>(qkv_w, wq_bf, 3 * DIM * DIM);
  gemm256<<<480, 512, 0, stream>>>(h_bf, wq_bf, qkv_b, nullptr, qkv_bf, SEQ, 3 * DIM, DIM);
  rope_qk<<<20480, 256, 0, stream>>>(qkv_bf, cosb, sinb, q_bf, k_bf);
  v_transpose<<<dim3(128, 5, 16), 256, 0, stream>>>(qkv_bf, v_tb);
  cast_f32_bf16<<<2048, 256, 0, stream>>>(proj_w, wp_bf, DIM * DIM);
  attn_kernel<<<1024, 256, 0, stream>>>(q_bf, k_bf, v_tb, attn_o);
  gemm_bt_bias<<<640, 256, 0, stream>>>(attn_o, wp_bf, proj_b, (float*)d_out, nullptr, SEQ, DIM, DIM);
}

// Round 23
// 298.858 us; speedup vs baseline: 1.2599x; 1.0082x over previous
//
#include <hip/hip_runtime.h>

#define SEQ 8192
#define DIM 1280
#define NHEADS 16
#define HD 80
#define HDP 96
#define NSEG 8
#define SEG 1024
#define KVB 64
#define NSTEP (SEG / KVB)
#define PST 72

typedef float f32x4 __attribute__((ext_vector_type(4)));
typedef short bf16x8 __attribute__((ext_vector_type(8)));
typedef unsigned int u32;

__device__ __forceinline__ float fast_exp2(float x) {
  return __builtin_amdgcn_exp2f(x);
}

__device__ __forceinline__ short f2bf(float f) {
  unsigned int u = __builtin_bit_cast(unsigned int, f);
  u = (u + 0x7fff + ((u >> 16) & 1)) >> 16;
  return (short)u;
}

__device__ __forceinline__ float bf2f(short s) {
  u32 u = ((u32)(unsigned short)s) << 16;
  return __builtin_bit_cast(float, u);
}

// packed f32x2 -> bf16x2 (RNE), D.lo = S0, D.hi = S1. No builtin on gfx950.
__device__ __forceinline__ u32 cvt_pk_bf16(float lo, float hi) {
  u32 r;
  asm("v_cvt_pk_bf16_f32 %0, %1, %2" : "=v"(r) : "v"(lo), "v"(hi));
  return r;
}

typedef __attribute__((address_space(1))) const unsigned int glds_src_t;
typedef __attribute__((address_space(3))) unsigned int glds_dst_t;
__device__ __forceinline__ void gload_lds16(const void* g, void* l) {
  __builtin_amdgcn_global_load_lds((glds_src_t*)g, (glds_dst_t*)l, 16, 0, 0);
}

// ---------------- generic f32 -> bf16 cast (vectorized) ----------------
__global__ void cast_f32_bf16(const float* __restrict__ in, short* __restrict__ out, int n) {
  int n4 = n >> 2;
  for (int i = blockIdx.x * blockDim.x + threadIdx.x; i < n4; i += gridDim.x * blockDim.x) {
    float4 v = ((const float4*)in)[i];
    short4 o;
    o.x = f2bf(v.x); o.y = f2bf(v.y); o.z = f2bf(v.z); o.w = f2bf(v.w);
    ((short4*)out)[i] = o;
  }
}

// ---------------- fused cast for hidden + qkv_w (both dests outside the
// qkv_bf clobber zone; proj_w must be cast AFTER gemm256 — see launch) ----
__global__ void cast2_f32_bf16(const float* __restrict__ a, short* __restrict__ oa, int na4,
                               const float* __restrict__ b, short* __restrict__ ob, int nb4) {
  int total = na4 + nb4;
  for (int i = blockIdx.x * blockDim.x + threadIdx.x; i < total; i += gridDim.x * blockDim.x) {
    const float4* src;
    short4* dst;
    int idx;
    if (i < na4) { src = (const float4*)a; dst = (short4*)oa; idx = i; }
    else { src = (const float4*)b; dst = (short4*)ob; idx = i - na4; }
    float4 v = src[idx];
    short4 o;
    o.x = f2bf(v.x); o.y = f2bf(v.y); o.z = f2bf(v.z); o.w = f2bf(v.w);
    dst[idx] = o;
  }
}

// ====== 256x256 bf16 GEMM, BK=32 dbuf, 64 KB LDS, 2 blocks/CU (r21-proven) ======
__global__ __launch_bounds__(512, 2) void gemm256(
    const short* __restrict__ A, const short* __restrict__ B,
    const float* __restrict__ bias, float* __restrict__ C,
    short* __restrict__ Cb, int M, int N, int K) {
  __shared__ short Sh[32768];  // 64 KB
  int tid = threadIdx.x;
  int w = tid >> 6, l = tid & 63;
  int lrow = l & 15, lg = l >> 4;
  int wm = w >> 2, wn = w & 3;
  int bid = blockIdx.x;
  int cpx = gridDim.x >> 3;
  int lid = (bid & 7) * cpx + (bid >> 3);
  int ntx = N >> 8;
  int m0 = (lid / ntx) * 256, n0 = (lid % ntx) * 256;

  const short* Ablk = A + (size_t)m0 * K;
  const short* Bblk = B + (size_t)n0 * K;

  f32x4 acc[8][4] = {};

#define STG32(BUF, OPB, GBASE, K0)                                            \
  {                                                                           \
    _Pragma("unroll") for (int rr = 0; rr < 2; rr++) {                        \
      int sb = rr * 512 + w * 64;                                             \
      int ss2 = sb + l;                                                       \
      int rl = ss2 >> 2, cc = ss2 & 3;                                        \
      int sl = cc ^ ((rl >> 1) & 3);                                          \
      const short* sp = (GBASE) + (size_t)rl * K + (K0) + sl * 8;             \
      gload_lds16(sp, (char*)Sh + (OPB)*32768 + (BUF)*16384 + sb * 16);       \
    }                                                                         \
  }
#define LDA32(MH)                                                             \
  _Pragma("unroll") for (int mt = 0; mt < 4; mt++) {                          \
    int rowa = wm * 128 + ((MH)*4 + mt) * 16 + lrow;                          \
    int pa_ = lg ^ ((rowa >> 1) & 3);                                         \
    a[mt] = *(const bf16x8*)&Sh[cur * 8192 + rowa * 32 + pa_ * 8];            \
  }
#define LDB32()                                                               \
  _Pragma("unroll") for (int nt = 0; nt < 4; nt++) {                          \
    int rowb = wn * 64 + nt * 16 + lrow;                                      \
    int pb_ = lg ^ ((rowb >> 1) & 3);                                         \
    b[nt] = *(const bf16x8*)&Sh[16384 + cur * 8192 + rowb * 32 + pb_ * 8];    \
  }
#define MFMA16X(MH)                                                           \
  _Pragma("unroll") for (int mt = 0; mt < 4; mt++)                            \
      _Pragma("unroll") for (int nt = 0; nt < 4; nt++)                        \
          acc[(MH)*4 + mt][nt] = __builtin_amdgcn_mfma_f32_16x16x32_bf16(     \
              a[mt], b[nt], acc[(MH)*4 + mt][nt], 0, 0, 0);

  STG32(0, 0, Ablk, 0);
  STG32(0, 1, Bblk, 0);
  asm volatile("s_waitcnt vmcnt(0)" ::: "memory");
  __builtin_amdgcn_s_barrier();
  asm volatile("" ::: "memory");

  int NT = K >> 5;
  for (int t = 0; t < NT; ++t) {
    int cur = t & 1;
    if (t + 1 < NT) {
      int k1 = (t + 1) << 5;
      STG32(cur ^ 1, 0, Ablk, k1);
      STG32(cur ^ 1, 1, Bblk, k1);
      asm volatile("s_waitcnt vmcnt(4)" ::: "memory");
    } else {
      asm volatile("s_waitcnt vmcnt(0)" ::: "memory");
    }
    __builtin_amdgcn_s_barrier();
    asm volatile("" ::: "memory");
    {
      bf16x8 a[4], b[4];
      __builtin_amdgcn_s_setprio(1);
      LDA32(0); LDB32(); MFMA16X(0);
      LDA32(1); MFMA16X(1);
      __builtin_amdgcn_s_setprio(0);
    }
    __builtin_amdgcn_s_barrier();
    asm volatile("" ::: "memory");
  }

  if (Cb) {
#pragma unroll
    for (int s = 0; s < 4; s++) {
      __syncthreads();
      if (wm == (s >> 1)) {
#pragma unroll
        for (int mi = 0; mi < 4; mi++) {
          int mt2 = (s & 1) * 4 + mi;
#pragma unroll
          for (int nt = 0; nt < 4; nt++) {
            int col = wn * 64 + nt * 16 + lrow;
            float bv = bias[n0 + col];
#pragma unroll
            for (int r = 0; r < 4; r++)
              Sh[(mi * 16 + lg * 4 + r) * 264 + col] = f2bf(acc[mt2][nt][r] + bv);
          }
        }
      }
      __syncthreads();
#pragma unroll
      for (int j = 0; j < 4; j++) {
        int c = j * 512 + tid;
        int row = c >> 5, ch = c & 31;
        *(uint4*)&Cb[(size_t)(m0 + s * 64 + row) * N + n0 + ch * 8] =
            *(const uint4*)&Sh[row * 264 + ch * 8];
      }
    }
  } else {
#pragma unroll
    for (int nt = 0; nt < 4; nt++) {
      int col = n0 + wn * 64 + nt * 16 + lrow;
      float bv = bias[col];
#pragma unroll
      for (int mt = 0; mt < 8; mt++) {
        int mrow = m0 + wm * 128 + mt * 16 + lg * 4;
#pragma unroll
        for (int r = 0; r < 4; r++)
          C[(size_t)(mrow + r) * N + col] = acc[mt][nt][r] + bv;
      }
    }
  }
#undef STG32
#undef LDA32
#undef LDB32
#undef MFMA16X
}

// ---------------- 128x128 bf16 GEMM (proj; r16-proven) ----------------
__global__ __launch_bounds__(256) void gemm_bt_bias(
    const short* __restrict__ A, const short* __restrict__ B,
    const float* __restrict__ bias, float* __restrict__ C,
    short* __restrict__ Cb, int M, int N, int K) {
  __shared__ short As[2][128 * 64];
  __shared__ short Bs[2][128 * 64];
  int tid = threadIdx.x;
  int w = tid >> 6, l = tid & 63;
  int lrow = l & 15, lg = l >> 4;
  int bid = blockIdx.x;
  int cpx = gridDim.x >> 3;
  int lid = (bid & 7) * cpx + (bid >> 3);
  int ntx = N >> 7;
  int m0 = (lid / ntx) * 128, n0 = (lid % ntx) * 128;
  int wm = w & 1, wn = w >> 1;

  f32x4 acc[4][4] = {};

  const char* Abase = (const char*)A + (size_t)m0 * K * 2;
  const char* Bbase = (const char*)B + (size_t)n0 * K * 2;

#define STAGE_G(BUF, K0)                                                       \
  {                                                                            \
    _Pragma("unroll") for (int j = 0; j < 4; j++) {                            \
      int c = j * 256 + tid;                                                   \
      int row = c >> 3;                                                        \
      int slc = (c & 7) ^ (row & 7);                                           \
      size_t goff = (size_t)row * K * 2 + (size_t)(K0) * 2 + slc * 16;         \
      int loff = (j * 256 + w * 64) * 16;                                      \
      gload_lds16(Abase + goff, (char*)&As[BUF][0] + loff);                    \
      gload_lds16(Bbase + goff, (char*)&Bs[BUF][0] + loff);                    \
    }                                                                          \
  }

  STAGE_G(0, 0);
  asm volatile("s_waitcnt vmcnt(0)" ::: "memory");
  __builtin_amdgcn_s_barrier();
  asm volatile("" ::: "memory");

  for (int k0 = 0; k0 < K; k0 += 64) {
    int cur = (k0 >> 6) & 1;
    if (k0 + 64 < K) {
      STAGE_G(cur ^ 1, k0 + 64);
      asm volatile("s_waitcnt vmcnt(8)" ::: "memory");
    } else {
      asm volatile("s_waitcnt vmcnt(0)" ::: "memory");
    }
    __builtin_amdgcn_s_barrier();
    asm volatile("" ::: "memory");
#pragma unroll
    for (int kk = 0; kk < 2; kk++) {
      bf16x8 a[4], b[4];
#pragma unroll
      for (int mt = 0; mt < 4; mt++) {
        int row = wm * 64 + mt * 16 + lrow;
        int p = (kk * 4 + lg) ^ (row & 7);
        a[mt] = *(const bf16x8*)&As[cur][row * 64 + p * 8];
      }
#pragma unroll
      for (int nt = 0; nt < 4; nt++) {
        int row = wn * 64 + nt * 16 + lrow;
        int p = (kk * 4 + lg) ^ (row & 7);
        b[nt] = *(const bf16x8*)&Bs[cur][row * 64 + p * 8];
      }
#pragma unroll
      for (int mt = 0; mt < 4; mt++)
#pragma unroll
        for (int nt = 0; nt < 4; nt++)
          acc[mt][nt] = __builtin_amdgcn_mfma_f32_16x16x32_bf16(a[mt], b[nt], acc[mt][nt], 0, 0, 0);
    }
    __builtin_amdgcn_s_barrier();
    asm volatile("" ::: "memory");
  }

#pragma unroll
  for (int nt = 0; nt < 4; nt++) {
    int col = n0 + wn * 64 + nt * 16 + lrow;
    float bv = bias[col];
#pragma unroll
    for (int mt = 0; mt < 4; mt++) {
      int mrow = m0 + wm * 64 + mt * 16 + lg * 4;
      if (Cb) {
#pragma unroll
        for (int r = 0; r < 4; r++)
          Cb[(size_t)(mrow + r) * N + col] = f2bf(acc[mt][nt][r] + bv);
      } else {
#pragma unroll
        for (int r = 0; r < 4; r++)
          C[(size_t)(mrow + r) * N + col] = acc[mt][nt][r] + bv;
      }
    }
  }
}

// ---------------- RoPE v2: vectorized (bf16x8 loads, packed bf16 stores) ----------------
// 5 threads per (s,h) row, each handling 8 of the 40 rotation pairs.
// Same f32 math per element as the scalar version (absmax-identical).
__global__ void rope_qk(const short* __restrict__ qkv, const float* __restrict__ cosb,
                        const float* __restrict__ sinb, short* __restrict__ qg,
                        short* __restrict__ kg) {
  int t = blockIdx.x * blockDim.x + threadIdx.x;
  if (t >= SEQ * NHEADS * 5) return;
  int j = t % 5;
  int h = (t / 5) & 15;
  int s = t / 80;
  int d0 = j * 8;
  const short* base = qkv + (size_t)s * (3 * DIM) + h * HD;
  bf16x8 x1 = *(const bf16x8*)&base[d0];
  bf16x8 x2 = *(const bf16x8*)&base[d0 + 40];
  bf16x8 y1 = *(const bf16x8*)&base[DIM + d0];
  bf16x8 y2 = *(const bf16x8*)&base[DIM + d0 + 40];
  const float* cb = cosb + s * HD;
  const float* sb = sinb + s * HD;
  const float sc = 0.11180339887498949f * 1.4426950408889634f;
  u32 qo0[4], qo1[4], ko0[4], ko1[4];
  float q0v[8], q1v[8], k0v[8], k1v[8];
#pragma unroll
  for (int i = 0; i < 8; i++) {
    float c0 = cb[d0 + i], c1 = cb[d0 + i + 40];
    float s0 = sb[d0 + i], s1 = sb[d0 + i + 40];
    float a1 = bf2f(x1[i]), a2 = bf2f(x2[i]);
    float b1 = bf2f(y1[i]), b2 = bf2f(y2[i]);
    q0v[i] = (a1 * c0 - a2 * s0) * sc;
    q1v[i] = (a2 * c1 + a1 * s1) * sc;
    k0v[i] = b1 * c0 - b2 * s0;
    k1v[i] = b2 * c1 + b1 * s1;
  }
#pragma unroll
  for (int i = 0; i < 4; i++) {
    qo0[i] = cvt_pk_bf16(q0v[2 * i], q0v[2 * i + 1]);
    qo1[i] = cvt_pk_bf16(q1v[2 * i], q1v[2 * i + 1]);
    ko0[i] = cvt_pk_bf16(k0v[2 * i], k0v[2 * i + 1]);
    ko1[i] = cvt_pk_bf16(k1v[2 * i], k1v[2 * i + 1]);
  }
  size_t ob = ((size_t)h * SEQ + s) * HDP;
  *(uint4*)&qg[ob + d0] = *(const uint4*)qo0;
  *(uint4*)&qg[ob + d0 + 40] = *(const uint4*)qo1;
  *(uint4*)&kg[ob + d0] = *(const uint4*)ko0;
  *(uint4*)&kg[ob + d0 + 40] = *(const uint4*)ko1;
  if (j == 4) {
    uint4 z = {0, 0, 0, 0};
    *(uint4*)&qg[ob + 80] = z;
    *(uint4*)&qg[ob + 88] = z;
    *(uint4*)&kg[ob + 80] = z;
    *(uint4*)&kg[ob + 88] = z;
  }
}

// ---------------- V transpose: qkv bf16 (S,3,H,80) -> vt bf16 (H,80,S) ----------------
__global__ void v_transpose(const short* __restrict__ qkv, short* __restrict__ vt) {
  __shared__ short T[16][72];
  int st = blockIdx.x, dt = blockIdx.y, h = blockIdx.z;
  int d0 = dt * 16, s0 = st * 64;
  int t = threadIdx.x;
  int dd = t & 15, ss = t >> 4;
#pragma unroll
  for (int j = 0; j < 4; j++) {
    int s = ss + j * 16;
    T[dd][s] = qkv[(size_t)(s0 + s) * (3 * DIM) + 2 * DIM + h * HD + d0 + dd];
  }
  __syncthreads();
  int s2 = t & 63, dr = t >> 6;
#pragma unroll
  for (int j = 0; j < 4; j++) {
    int d = dr + j * 4;
    vt[((size_t)(h * HD + d0 + d)) * SEQ + s0 + s2] = T[d][s2];
  }
}

// ---------------- flash attention v8 (r20/r21-proven: 4 waves, 2 blocks/CU) ----------------
__global__ __launch_bounds__(256, 2) void attn_kernel(
    const short* __restrict__ qg, const short* __restrict__ kg,
    const short* __restrict__ vt, short* __restrict__ out) {
  __shared__ short Ks[2][64 * 128];  // 32 KB
  __shared__ short Pl[4][32 * PST];  // 18 KB
  int bid = blockIdx.x;
  int b = bid & 7, h = (bid >> 3) & 15, qt = bid >> 7;
  int tid = threadIdx.x;
  int w = tid >> 6, l = tid & 63;
  int lrow = l & 15, lg = l >> 4;
  int qbase_s = b * SEG + qt * 128 + w * 32;

  const short* qh = qg + (size_t)h * SEQ * HDP;
  const short* kh = kg + (size_t)h * SEQ * HDP;
  const short* vh = vt + (size_t)h * HD * SEQ;

#define STAGE_K(BUF, KEY0N)                                                    \
  {                                                                            \
    _Pragma("unroll") for (int sr = 0; sr < 4; sr++) {                         \
      int sbase = sr * 256 + w * 64;                                           \
      int ss = sbase + l;                                                      \
      int skey = ss >> 4, sc = ss & 15;                                        \
      int slc = sc ^ (skey & 7);                                               \
      const short* ssrc =                                                      \
          kh + (size_t)((KEY0N) + skey) * HDP + (slc < 12 ? slc * 8 : 0);      \
      gload_lds16(ssrc, (char*)&Ks[BUF][0] + sbase * 16);                      \
    }                                                                          \
  }

  bf16x8 qf[2][3];
#pragma unroll
  for (int mt = 0; mt < 2; mt++)
#pragma unroll
    for (int ks = 0; ks < 3; ks++)
      qf[mt][ks] = *(const bf16x8*)&qh[(size_t)(qbase_s + mt * 16 + lrow) * HDP + ks * 32 + lg * 8];

  f32x4 o[2][5] = {};
  float m_st[2] = {-1e30f, -1e30f};
  float l_st[2] = {0.f, 0.f};

  short* Pw = &Pl[w][0];

  STAGE_K(0, b * SEG);
  __syncthreads();

  for (int i = 0; i < NSTEP; i++) {
    int cur = i & 1;
    int key0 = b * SEG + i * KVB;
    if (i + 1 < NSTEP) {
      STAGE_K(cur ^ 1, key0 + KVB);
    }

    f32x4 sv[2][4] = {};
    __builtin_amdgcn_s_setprio(1);
#pragma unroll
    for (int kt = 0; kt < 4; kt++) {
      bf16x8 kf[3];
      int key = kt * 16 + lrow;
#pragma unroll
      for (int ks = 0; ks < 3; ks++) {
        int p = (ks * 4 + lg) ^ (key & 7);
        kf[ks] = *(const bf16x8*)&Ks[cur][key * 128 + p * 8];
      }
#pragma unroll
      for (int mt = 0; mt < 2; mt++)
#pragma unroll
        for (int ks = 0; ks < 3; ks++)
          sv[mt][kt] = __builtin_amdgcn_mfma_f32_16x16x32_bf16(kf[ks], qf[mt][ks], sv[mt][kt], 0, 0, 0);
    }
    __builtin_amdgcn_s_setprio(0);

    bf16x8 vf[5][2];
#pragma unroll
    for (int nt = 0; nt < 5; nt++)
#pragma unroll
      for (int ks = 0; ks < 2; ks++)
        vf[nt][ks] = *(const bf16x8*)&vh[(size_t)(nt * 16 + lrow) * SEQ + key0 + ks * 32 + lg * 8];

    float cm[2];
#pragma unroll
    for (int mt = 0; mt < 2; mt++) {
      float a0 = fmaxf(fmaxf(sv[mt][0][0], sv[mt][0][1]), fmaxf(sv[mt][0][2], sv[mt][0][3]));
      float a1 = fmaxf(fmaxf(sv[mt][1][0], sv[mt][1][1]), fmaxf(sv[mt][1][2], sv[mt][1][3]));
      float a2 = fmaxf(fmaxf(sv[mt][2][0], sv[mt][2][1]), fmaxf(sv[mt][2][2], sv[mt][2][3]));
      float a3 = fmaxf(fmaxf(sv[mt][3][0], sv[mt][3][1]), fmaxf(sv[mt][3][2], sv[mt][3][3]));
      float c = fmaxf(fmaxf(a0, a1), fmaxf(a2, a3));
      c = fmaxf(c, __shfl_xor(c, 16));
      c = fmaxf(c, __shfl_xor(c, 32));
      cm[mt] = c;
    }
    if (__any((cm[0] > m_st[0] + 8.f) || (cm[1] > m_st[1] + 8.f))) {
#pragma unroll
      for (int mt = 0; mt < 2; mt++) {
        float mn = fmaxf(m_st[mt], cm[mt]);
        float c = fast_exp2(m_st[mt] - mn);
        m_st[mt] = mn;
        l_st[mt] *= c;
        float cr[4];
#pragma unroll
        for (int r = 0; r < 4; r++) cr[r] = __shfl(c, lg * 4 + r);
#pragma unroll
        for (int nt = 0; nt < 5; nt++)
#pragma unroll
          for (int r = 0; r < 4; r++) o[mt][nt][r] *= cr[r];
      }
    }
#pragma unroll
    for (int mt = 0; mt < 2; mt++) {
      float rs = 0.f;
#pragma unroll
      for (int kt = 0; kt < 4; kt++) {
#pragma unroll
        for (int r = 0; r < 4; r++) {
          sv[mt][kt][r] = fast_exp2(sv[mt][kt][r] - m_st[mt]);
          rs += sv[mt][kt][r];
        }
        uint2 pk;
        pk.x = cvt_pk_bf16(sv[mt][kt][0], sv[mt][kt][1]);
        pk.y = cvt_pk_bf16(sv[mt][kt][2], sv[mt][kt][3]);
        *(uint2*)&Pw[(mt * 16 + lrow) * PST + kt * 16 + lg * 4] = pk;
      }
      rs += __shfl_xor(rs, 16);
      rs += __shfl_xor(rs, 32);
      l_st[mt] += rs;
    }

    bf16x8 pa[2][2];
#pragma unroll
    for (int mt = 0; mt < 2; mt++)
#pragma unroll
      for (int ks = 0; ks < 2; ks++)
        pa[mt][ks] = *(const bf16x8*)&Pw[(mt * 16 + lrow) * PST + ks * 32 + lg * 8];
    __builtin_amdgcn_s_setprio(1);
#pragma unroll
    for (int nt = 0; nt < 5; nt++)
#pragma unroll
      for (int mt = 0; mt < 2; mt++)
#pragma unroll
        for (int ks = 0; ks < 2; ks++)
          o[mt][nt] = __builtin_amdgcn_mfma_f32_16x16x32_bf16(pa[mt][ks], vf[nt][ks], o[mt][nt], 0, 0, 0);
    __builtin_amdgcn_s_setprio(0);

    __syncthreads();
  }

#pragma unroll
  for (int mt = 0; mt < 2; mt++) {
    float rl = 1.f / l_st[mt];
    float ir[4];
#pragma unroll
    for (int r = 0; r < 4; r++) ir[r] = __shfl(rl, lg * 4 + r);
#pragma unroll
    for (int r = 0; r < 4; r++) {
      int srow = qbase_s + mt * 16 + lg * 4 + r;
#pragma unroll
      for (int nt = 0; nt < 5; nt++)
        out[(size_t)srow * DIM + h * HD + nt * 16 + lrow] = f2bf(o[mt][nt][r] * ir[r]);
    }
  }
}

extern "C" void kernel_launch(void* const* d_in, const int* in_sizes, int n_in,
                              void* d_out, int out_size, void* d_ws, size_t ws_size,
                              hipStream_t stream) {
  const float* hidden = (const float*)d_in[0];
  const float* cosb = (const float*)d_in[1];
  const float* sinb = (const float*)d_in[2];
  const float* qkv_w = (const float*)d_in[3];
  const float* qkv_b = (const float*)d_in[4];
  const float* proj_w = (const float*)d_in[5];
  const float* proj_b = (const float*)d_in[6];

  char* ws = (char*)d_ws;
  short* qkv_bf = (short*)(ws);            // [0, 62.9MB) — written by gemm256
  short* attn_o = (short*)(ws);            // [0, 21MB) — written by attn
  short* wp_bf = (short*)(ws + 23068672);  // inside qkv zone: MUST be cast
                                           // after gemm256 (r22 bug: cast
                                           // first -> clobbered by qkv)
  short* q_bf = (short*)(ws + 125829120);
  short* k_bf = (short*)(ws + 150994944);
  short* v_tb = (short*)(ws + 176160768);
  short* h_bf = (short*)(ws + 197132288);
  short* wq_bf = (short*)(ws + 218103808);

  cast2_f32_bf16<<<2048, 256, 0, stream>>>(hidden, h_bf, (SEQ * DIM) / 4,
                                           qkv_w, wq_bf, (3 * DIM * DIM) / 4);
  gemm256<<<480, 512, 0, stream>>>(h_bf, wq_bf, qkv_b, nullptr, qkv_bf, SEQ, 3 * DIM, DIM);
  rope_qk<<<2560, 256, 0, stream>>>(qkv_bf, cosb, sinb, q_bf, k_bf);
  v_transpose<<<dim3(128, 5, 16), 256, 0, stream>>>(qkv_bf, v_tb);
  cast_f32_bf16<<<1024, 256, 0, stream>>>(proj_w, wp_bf, DIM * DIM);
  attn_kernel<<<1024, 256, 0, stream>>>(q_bf, k_bf, v_tb, attn_o);
  gemm_bt_bias<<<640, 256, 0, stream>>>(attn_o, wp_bf, proj_b, (float*)d_out, nullptr, SEQ, DIM, DIM);
}

// Round 24
// 289.357 us; speedup vs baseline: 1.3013x; 1.0328x over previous
//
#include <hip/hip_runtime.h>

#define SEQ 8192
#define DIM 1280
#define NHEADS 16
#define HD 80
#define HDP 96
#define NSEG 8
#define SEG 1024
#define KVB 64
#define NSTEP (SEG / KVB)
#define PST 72

typedef float f32x4 __attribute__((ext_vector_type(4)));
typedef short bf16x8 __attribute__((ext_vector_type(8)));
typedef unsigned int u32;

__device__ __forceinline__ float fast_exp2(float x) {
  return __builtin_amdgcn_exp2f(x);
}

__device__ __forceinline__ short f2bf(float f) {
  unsigned int u = __builtin_bit_cast(unsigned int, f);
  u = (u + 0x7fff + ((u >> 16) & 1)) >> 16;
  return (short)u;
}

__device__ __forceinline__ float bf2f(short s) {
  u32 u = ((u32)(unsigned short)s) << 16;
  return __builtin_bit_cast(float, u);
}

// packed f32x2 -> bf16x2 (RNE), D.lo = S0, D.hi = S1. No builtin on gfx950.
__device__ __forceinline__ u32 cvt_pk_bf16(float lo, float hi) {
  u32 r;
  asm("v_cvt_pk_bf16_f32 %0, %1, %2" : "=v"(r) : "v"(lo), "v"(hi));
  return r;
}

typedef __attribute__((address_space(1))) const unsigned int glds_src_t;
typedef __attribute__((address_space(3))) unsigned int glds_dst_t;
__device__ __forceinline__ void gload_lds16(const void* g, void* l) {
  __builtin_amdgcn_global_load_lds((glds_src_t*)g, (glds_dst_t*)l, 16, 0, 0);
}

// ---------------- generic f32 -> bf16 cast (vectorized) ----------------
__global__ void cast_f32_bf16(const float* __restrict__ in, short* __restrict__ out, int n) {
  int n4 = n >> 2;
  for (int i = blockIdx.x * blockDim.x + threadIdx.x; i < n4; i += gridDim.x * blockDim.x) {
    float4 v = ((const float4*)in)[i];
    short4 o;
    o.x = f2bf(v.x); o.y = f2bf(v.y); o.z = f2bf(v.z); o.w = f2bf(v.w);
    ((short4*)out)[i] = o;
  }
}

// ---------------- fused cast for hidden + qkv_w (both dests outside the
// qkv_bf clobber zone; proj_w must be cast AFTER gemm256 — see launch) ----
__global__ void cast2_f32_bf16(const float* __restrict__ a, short* __restrict__ oa, int na4,
                               const float* __restrict__ b, short* __restrict__ ob, int nb4) {
  int total = na4 + nb4;
  for (int i = blockIdx.x * blockDim.x + threadIdx.x; i < total; i += gridDim.x * blockDim.x) {
    const float4* src;
    short4* dst;
    int idx;
    if (i < na4) { src = (const float4*)a; dst = (short4*)oa; idx = i; }
    else { src = (const float4*)b; dst = (short4*)ob; idx = i - na4; }
    float4 v = src[idx];
    short4 o;
    o.x = f2bf(v.x); o.y = f2bf(v.y); o.z = f2bf(v.z); o.w = f2bf(v.w);
    dst[idx] = o;
  }
}

// ====== 256x256 bf16 GEMM, BK=32 dbuf, 64 KB LDS, 2 blocks/CU (r21-proven) ======
__global__ __launch_bounds__(512, 2) void gemm256(
    const short* __restrict__ A, const short* __restrict__ B,
    const float* __restrict__ bias, float* __restrict__ C,
    short* __restrict__ Cb, int M, int N, int K) {
  __shared__ short Sh[32768];  // 64 KB
  int tid = threadIdx.x;
  int w = tid >> 6, l = tid & 63;
  int lrow = l & 15, lg = l >> 4;
  int wm = w >> 2, wn = w & 3;
  int bid = blockIdx.x;
  int cpx = gridDim.x >> 3;
  int lid = (bid & 7) * cpx + (bid >> 3);
  int ntx = N >> 8;
  int m0 = (lid / ntx) * 256, n0 = (lid % ntx) * 256;

  const short* Ablk = A + (size_t)m0 * K;
  const short* Bblk = B + (size_t)n0 * K;

  f32x4 acc[8][4] = {};

#define STG32(BUF, OPB, GBASE, K0)                                            \
  {                                                                           \
    _Pragma("unroll") for (int rr = 0; rr < 2; rr++) {                        \
      int sb = rr * 512 + w * 64;                                             \
      int ss2 = sb + l;                                                       \
      int rl = ss2 >> 2, cc = ss2 & 3;                                        \
      int sl = cc ^ ((rl >> 1) & 3);                                          \
      const short* sp = (GBASE) + (size_t)rl * K + (K0) + sl * 8;             \
      gload_lds16(sp, (char*)Sh + (OPB)*32768 + (BUF)*16384 + sb * 16);       \
    }                                                                         \
  }
#define LDA32(MH)                                                             \
  _Pragma("unroll") for (int mt = 0; mt < 4; mt++) {                          \
    int rowa = wm * 128 + ((MH)*4 + mt) * 16 + lrow;                          \
    int pa_ = lg ^ ((rowa >> 1) & 3);                                         \
    a[mt] = *(const bf16x8*)&Sh[cur * 8192 + rowa * 32 + pa_ * 8];            \
  }
#define LDB32()                                                               \
  _Pragma("unroll") for (int nt = 0; nt < 4; nt++) {                          \
    int rowb = wn * 64 + nt * 16 + lrow;                                      \
    int pb_ = lg ^ ((rowb >> 1) & 3);                                         \
    b[nt] = *(const bf16x8*)&Sh[16384 + cur * 8192 + rowb * 32 + pb_ * 8];    \
  }
#define MFMA16X(MH)                                                           \
  _Pragma("unroll") for (int mt = 0; mt < 4; mt++)                            \
      _Pragma("unroll") for (int nt = 0; nt < 4; nt++)                        \
          acc[(MH)*4 + mt][nt] = __builtin_amdgcn_mfma_f32_16x16x32_bf16(     \
              a[mt], b[nt], acc[(MH)*4 + mt][nt], 0, 0, 0);

  STG32(0, 0, Ablk, 0);
  STG32(0, 1, Bblk, 0);
  asm volatile("s_waitcnt vmcnt(0)" ::: "memory");
  __builtin_amdgcn_s_barrier();
  asm volatile("" ::: "memory");

  int NT = K >> 5;
  for (int t = 0; t < NT; ++t) {
    int cur = t & 1;
    if (t + 1 < NT) {
      int k1 = (t + 1) << 5;
      STG32(cur ^ 1, 0, Ablk, k1);
      STG32(cur ^ 1, 1, Bblk, k1);
      asm volatile("s_waitcnt vmcnt(4)" ::: "memory");
    } else {
      asm volatile("s_waitcnt vmcnt(0)" ::: "memory");
    }
    __builtin_amdgcn_s_barrier();
    asm volatile("" ::: "memory");
    {
      bf16x8 a[4], b[4];
      __builtin_amdgcn_s_setprio(1);
      LDA32(0); LDB32(); MFMA16X(0);
      LDA32(1); MFMA16X(1);
      __builtin_amdgcn_s_setprio(0);
    }
    __builtin_amdgcn_s_barrier();
    asm volatile("" ::: "memory");
  }

  if (Cb) {
#pragma unroll
    for (int s = 0; s < 4; s++) {
      __syncthreads();
      if (wm == (s >> 1)) {
#pragma unroll
        for (int mi = 0; mi < 4; mi++) {
          int mt2 = (s & 1) * 4 + mi;
#pragma unroll
          for (int nt = 0; nt < 4; nt++) {
            int col = wn * 64 + nt * 16 + lrow;
            float bv = bias[n0 + col];
#pragma unroll
            for (int r = 0; r < 4; r++)
              Sh[(mi * 16 + lg * 4 + r) * 264 + col] = f2bf(acc[mt2][nt][r] + bv);
          }
        }
      }
      __syncthreads();
#pragma unroll
      for (int j = 0; j < 4; j++) {
        int c = j * 512 + tid;
        int row = c >> 5, ch = c & 31;
        *(uint4*)&Cb[(size_t)(m0 + s * 64 + row) * N + n0 + ch * 8] =
            *(const uint4*)&Sh[row * 264 + ch * 8];
      }
    }
  } else {
#pragma unroll
    for (int nt = 0; nt < 4; nt++) {
      int col = n0 + wn * 64 + nt * 16 + lrow;
      float bv = bias[col];
#pragma unroll
      for (int mt = 0; mt < 8; mt++) {
        int mrow = m0 + wm * 128 + mt * 16 + lg * 4;
#pragma unroll
        for (int r = 0; r < 4; r++)
          C[(size_t)(mrow + r) * N + col] = acc[mt][nt][r] + bv;
      }
    }
  }
#undef STG32
#undef LDA32
#undef LDB32
#undef MFMA16X
}

// ---------------- 128x128 bf16 GEMM (proj; r16-proven) ----------------
__global__ __launch_bounds__(256) void gemm_bt_bias(
    const short* __restrict__ A, const short* __restrict__ B,
    const float* __restrict__ bias, float* __restrict__ C,
    short* __restrict__ Cb, int M, int N, int K) {
  __shared__ short As[2][128 * 64];
  __shared__ short Bs[2][128 * 64];
  int tid = threadIdx.x;
  int w = tid >> 6, l = tid & 63;
  int lrow = l & 15, lg = l >> 4;
  int bid = blockIdx.x;
  int cpx = gridDim.x >> 3;
  int lid = (bid & 7) * cpx + (bid >> 3);
  int ntx = N >> 7;
  int m0 = (lid / ntx) * 128, n0 = (lid % ntx) * 128;
  int wm = w & 1, wn = w >> 1;

  f32x4 acc[4][4] = {};

  const char* Abase = (const char*)A + (size_t)m0 * K * 2;
  const char* Bbase = (const char*)B + (size_t)n0 * K * 2;

#define STAGE_G(BUF, K0)                                                       \
  {                                                                            \
    _Pragma("unroll") for (int j = 0; j < 4; j++) {                            \
      int c = j * 256 + tid;                                                   \
      int row = c >> 3;                                                        \
      int slc = (c & 7) ^ (row & 7);                                           \
      size_t goff = (size_t)row * K * 2 + (size_t)(K0) * 2 + slc * 16;         \
      int loff = (j * 256 + w * 64) * 16;                                      \
      gload_lds16(Abase + goff, (char*)&As[BUF][0] + loff);                    \
      gload_lds16(Bbase + goff, (char*)&Bs[BUF][0] + loff);                    \
    }                                                                          \
  }

  STAGE_G(0, 0);
  asm volatile("s_waitcnt vmcnt(0)" ::: "memory");
  __builtin_amdgcn_s_barrier();
  asm volatile("" ::: "memory");

  for (int k0 = 0; k0 < K; k0 += 64) {
    int cur = (k0 >> 6) & 1;
    if (k0 + 64 < K) {
      STAGE_G(cur ^ 1, k0 + 64);
      asm volatile("s_waitcnt vmcnt(8)" ::: "memory");
    } else {
      asm volatile("s_waitcnt vmcnt(0)" ::: "memory");
    }
    __builtin_amdgcn_s_barrier();
    asm volatile("" ::: "memory");
#pragma unroll
    for (int kk = 0; kk < 2; kk++) {
      bf16x8 a[4], b[4];
#pragma unroll
      for (int mt = 0; mt < 4; mt++) {
        int row = wm * 64 + mt * 16 + lrow;
        int p = (kk * 4 + lg) ^ (row & 7);
        a[mt] = *(const bf16x8*)&As[cur][row * 64 + p * 8];
      }
#pragma unroll
      for (int nt = 0; nt < 4; nt++) {
        int row = wn * 64 + nt * 16 + lrow;
        int p = (kk * 4 + lg) ^ (row & 7);
        b[nt] = *(const bf16x8*)&Bs[cur][row * 64 + p * 8];
      }
#pragma unroll
      for (int mt = 0; mt < 4; mt++)
#pragma unroll
        for (int nt = 0; nt < 4; nt++)
          acc[mt][nt] = __builtin_amdgcn_mfma_f32_16x16x32_bf16(a[mt], b[nt], acc[mt][nt], 0, 0, 0);
    }
    __builtin_amdgcn_s_barrier();
    asm volatile("" ::: "memory");
  }

#pragma unroll
  for (int nt = 0; nt < 4; nt++) {
    int col = n0 + wn * 64 + nt * 16 + lrow;
    float bv = bias[col];
#pragma unroll
    for (int mt = 0; mt < 4; mt++) {
      int mrow = m0 + wm * 64 + mt * 16 + lg * 4;
      if (Cb) {
#pragma unroll
        for (int r = 0; r < 4; r++)
          Cb[(size_t)(mrow + r) * N + col] = f2bf(acc[mt][nt][r] + bv);
      } else {
#pragma unroll
        for (int r = 0; r < 4; r++)
          C[(size_t)(mrow + r) * N + col] = acc[mt][nt][r] + bv;
      }
    }
  }
}

// ---------------- RoPE v2: vectorized (r23-proven) ----------------
__global__ void rope_qk(const short* __restrict__ qkv, const float* __restrict__ cosb,
                        const float* __restrict__ sinb, short* __restrict__ qg,
                        short* __restrict__ kg) {
  int t = blockIdx.x * blockDim.x + threadIdx.x;
  if (t >= SEQ * NHEADS * 5) return;
  int j = t % 5;
  int h = (t / 5) & 15;
  int s = t / 80;
  int d0 = j * 8;
  const short* base = qkv + (size_t)s * (3 * DIM) + h * HD;
  bf16x8 x1 = *(const bf16x8*)&base[d0];
  bf16x8 x2 = *(const bf16x8*)&base[d0 + 40];
  bf16x8 y1 = *(const bf16x8*)&base[DIM + d0];
  bf16x8 y2 = *(const bf16x8*)&base[DIM + d0 + 40];
  const float* cb = cosb + s * HD;
  const float* sb = sinb + s * HD;
  const float sc = 0.11180339887498949f * 1.4426950408889634f;
  u32 qo0[4], qo1[4], ko0[4], ko1[4];
  float q0v[8], q1v[8], k0v[8], k1v[8];
#pragma unroll
  for (int i = 0; i < 8; i++) {
    float c0 = cb[d0 + i], c1 = cb[d0 + i + 40];
    float s0 = sb[d0 + i], s1 = sb[d0 + i + 40];
    float a1 = bf2f(x1[i]), a2 = bf2f(x2[i]);
    float b1 = bf2f(y1[i]), b2 = bf2f(y2[i]);
    q0v[i] = (a1 * c0 - a2 * s0) * sc;
    q1v[i] = (a2 * c1 + a1 * s1) * sc;
    k0v[i] = b1 * c0 - b2 * s0;
    k1v[i] = b2 * c1 + b1 * s1;
  }
#pragma unroll
  for (int i = 0; i < 4; i++) {
    qo0[i] = cvt_pk_bf16(q0v[2 * i], q0v[2 * i + 1]);
    qo1[i] = cvt_pk_bf16(q1v[2 * i], q1v[2 * i + 1]);
    ko0[i] = cvt_pk_bf16(k0v[2 * i], k0v[2 * i + 1]);
    ko1[i] = cvt_pk_bf16(k1v[2 * i], k1v[2 * i + 1]);
  }
  size_t ob = ((size_t)h * SEQ + s) * HDP;
  *(uint4*)&qg[ob + d0] = *(const uint4*)qo0;
  *(uint4*)&qg[ob + d0 + 40] = *(const uint4*)qo1;
  *(uint4*)&kg[ob + d0] = *(const uint4*)ko0;
  *(uint4*)&kg[ob + d0 + 40] = *(const uint4*)ko1;
  if (j == 4) {
    uint4 z = {0, 0, 0, 0};
    *(uint4*)&qg[ob + 80] = z;
    *(uint4*)&qg[ob + 88] = z;
    *(uint4*)&kg[ob + 80] = z;
    *(uint4*)&kg[ob + 88] = z;
  }
}

// ---------------- V transpose: qkv bf16 (S,3,H,80) -> vt bf16 (H,80,S) ----------------
__global__ void v_transpose(const short* __restrict__ qkv, short* __restrict__ vt) {
  __shared__ short T[16][72];
  int st = blockIdx.x, dt = blockIdx.y, h = blockIdx.z;
  int d0 = dt * 16, s0 = st * 64;
  int t = threadIdx.x;
  int dd = t & 15, ss = t >> 4;
#pragma unroll
  for (int j = 0; j < 4; j++) {
    int s = ss + j * 16;
    T[dd][s] = qkv[(size_t)(s0 + s) * (3 * DIM) + 2 * DIM + h * HD + d0 + dd];
  }
  __syncthreads();
  int s2 = t & 63, dr = t >> 6;
#pragma unroll
  for (int j = 0; j < 4; j++) {
    int d = dr + j * 4;
    vt[((size_t)(h * HD + d0 + d)) * SEQ + s0 + s2] = T[d][s2];
  }
}

// ---------------- flash attention v9: gemm-geometry K LDS ----------------
// = v8 (4 waves, 2 blocks/CU) with the K LDS re-laid to the gemm-proven
// bank pattern: row stride 12 slots (96 shorts = 192B = 48 dw == 16 mod 32
// banks) instead of 16 slots (256B == 0 mod 32 -> all rows same bank base,
// ~8-way serialization on every fragment read: attn counted 6.29M
// conflicts/dispatch vs gemm's 0). No pad (HDP=96 = exactly 12 chunks).
// Stage swizzle slc = sc ^ ((skey>>1)&3) (bijective within aligned 4-chunk
// groups); read applies the same involution. 768 slots = 3 rounds x 256.
__global__ __launch_bounds__(256, 2) void attn_kernel(
    const short* __restrict__ qg, const short* __restrict__ kg,
    const short* __restrict__ vt, short* __restrict__ out) {
  __shared__ short Ks[2][64 * 96];   // 24 KB
  __shared__ short Pl[4][32 * PST];  // 18 KB
  int bid = blockIdx.x;
  int b = bid & 7, h = (bid >> 3) & 15, qt = bid >> 7;
  int tid = threadIdx.x;
  int w = tid >> 6, l = tid & 63;
  int lrow = l & 15, lg = l >> 4;
  int qbase_s = b * SEG + qt * 128 + w * 32;

  const short* qh = qg + (size_t)h * SEQ * HDP;
  const short* kh = kg + (size_t)h * SEQ * HDP;
  const short* vh = vt + (size_t)h * HD * SEQ;

  // K stage: 768 slots x 16B, 3 rounds of 256 threads. Row = 12 slots.
#define STAGE_K(BUF, KEY0N)                                                    \
  {                                                                            \
    _Pragma("unroll") for (int sr = 0; sr < 3; sr++) {                         \
      int sbase = sr * 256 + w * 64;                                           \
      int ss = sbase + l;                                                      \
      int skey = ss / 12, sc = ss % 12;                                        \
      int slc = sc ^ ((skey >> 1) & 3);                                        \
      const short* ssrc = kh + (size_t)((KEY0N) + skey) * HDP + slc * 8;       \
      gload_lds16(ssrc, (char*)&Ks[BUF][0] + sbase * 16);                      \
    }                                                                          \
  }

  bf16x8 qf[2][3];
#pragma unroll
  for (int mt = 0; mt < 2; mt++)
#pragma unroll
    for (int ks = 0; ks < 3; ks++)
      qf[mt][ks] = *(const bf16x8*)&qh[(size_t)(qbase_s + mt * 16 + lrow) * HDP + ks * 32 + lg * 8];

  f32x4 o[2][5] = {};
  float m_st[2] = {-1e30f, -1e30f};
  float l_st[2] = {0.f, 0.f};

  short* Pw = &Pl[w][0];

  STAGE_K(0, b * SEG);
  __syncthreads();

  for (int i = 0; i < NSTEP; i++) {
    int cur = i & 1;
    int key0 = b * SEG + i * KVB;
    if (i + 1 < NSTEP) {
      STAGE_K(cur ^ 1, key0 + KVB);
    }

    f32x4 sv[2][4] = {};
    __builtin_amdgcn_s_setprio(1);
#pragma unroll
    for (int kt = 0; kt < 4; kt++) {
      bf16x8 kf[3];
      int key = kt * 16 + lrow;
#pragma unroll
      for (int ks = 0; ks < 3; ks++) {
        int p = (ks * 4 + lg) ^ ((key >> 1) & 3);
        kf[ks] = *(const bf16x8*)&Ks[cur][key * 96 + p * 8];
      }
#pragma unroll
      for (int mt = 0; mt < 2; mt++)
#pragma unroll
        for (int ks = 0; ks < 3; ks++)
          sv[mt][kt] = __builtin_amdgcn_mfma_f32_16x16x32_bf16(kf[ks], qf[mt][ks], sv[mt][kt], 0, 0, 0);
    }
    __builtin_amdgcn_s_setprio(0);

    bf16x8 vf[5][2];
#pragma unroll
    for (int nt = 0; nt < 5; nt++)
#pragma unroll
      for (int ks = 0; ks < 2; ks++)
        vf[nt][ks] = *(const bf16x8*)&vh[(size_t)(nt * 16 + lrow) * SEQ + key0 + ks * 32 + lg * 8];

    float cm[2];
#pragma unroll
    for (int mt = 0; mt < 2; mt++) {
      float a0 = fmaxf(fmaxf(sv[mt][0][0], sv[mt][0][1]), fmaxf(sv[mt][0][2], sv[mt][0][3]));
      float a1 = fmaxf(fmaxf(sv[mt][1][0], sv[mt][1][1]), fmaxf(sv[mt][1][2], sv[mt][1][3]));
      float a2 = fmaxf(fmaxf(sv[mt][2][0], sv[mt][2][1]), fmaxf(sv[mt][2][2], sv[mt][2][3]));
      float a3 = fmaxf(fmaxf(sv[mt][3][0], sv[mt][3][1]), fmaxf(sv[mt][3][2], sv[mt][3][3]));
      float c = fmaxf(fmaxf(a0, a1), fmaxf(a2, a3));
      c = fmaxf(c, __shfl_xor(c, 16));
      c = fmaxf(c, __shfl_xor(c, 32));
      cm[mt] = c;
    }
    if (__any((cm[0] > m_st[0] + 8.f) || (cm[1] > m_st[1] + 8.f))) {
#pragma unroll
      for (int mt = 0; mt < 2; mt++) {
        float mn = fmaxf(m_st[mt], cm[mt]);
        float c = fast_exp2(m_st[mt] - mn);
        m_st[mt] = mn;
        l_st[mt] *= c;
        float cr[4];
#pragma unroll
        for (int r = 0; r < 4; r++) cr[r] = __shfl(c, lg * 4 + r);
#pragma unroll
        for (int nt = 0; nt < 5; nt++)
#pragma unroll
          for (int r = 0; r < 4; r++) o[mt][nt][r] *= cr[r];
      }
    }
#pragma unroll
    for (int mt = 0; mt < 2; mt++) {
      float rs = 0.f;
#pragma unroll
      for (int kt = 0; kt < 4; kt++) {
#pragma unroll
        for (int r = 0; r < 4; r++) {
          sv[mt][kt][r] = fast_exp2(sv[mt][kt][r] - m_st[mt]);
          rs += sv[mt][kt][r];
        }
        uint2 pk;
        pk.x = cvt_pk_bf16(sv[mt][kt][0], sv[mt][kt][1]);
        pk.y = cvt_pk_bf16(sv[mt][kt][2], sv[mt][kt][3]);
        *(uint2*)&Pw[(mt * 16 + lrow) * PST + kt * 16 + lg * 4] = pk;
      }
      rs += __shfl_xor(rs, 16);
      rs += __shfl_xor(rs, 32);
      l_st[mt] += rs;
    }

    bf16x8 pa[2][2];
#pragma unroll
    for (int mt = 0; mt < 2; mt++)
#pragma unroll
      for (int ks = 0; ks < 2; ks++)
        pa[mt][ks] = *(const bf16x8*)&Pw[(mt * 16 + lrow) * PST + ks * 32 + lg * 8];
    __builtin_amdgcn_s_setprio(1);
#pragma unroll
    for (int nt = 0; nt < 5; nt++)
#pragma unroll
      for (int mt = 0; mt < 2; mt++)
#pragma unroll
        for (int ks = 0; ks < 2; ks++)
          o[mt][nt] = __builtin_amdgcn_mfma_f32_16x16x32_bf16(pa[mt][ks], vf[nt][ks], o[mt][nt], 0, 0, 0);
    __builtin_amdgcn_s_setprio(0);

    __syncthreads();
  }

#pragma unroll
  for (int mt = 0; mt < 2; mt++) {
    float rl = 1.f / l_st[mt];
    float ir[4];
#pragma unroll
    for (int r = 0; r < 4; r++) ir[r] = __shfl(rl, lg * 4 + r);
#pragma unroll
    for (int r = 0; r < 4; r++) {
      int srow = qbase_s + mt * 16 + lg * 4 + r;
#pragma unroll
      for (int nt = 0; nt < 5; nt++)
        out[(size_t)srow * DIM + h * HD + nt * 16 + lrow] = f2bf(o[mt][nt][r] * ir[r]);
    }
  }
}

extern "C" void kernel_launch(void* const* d_in, const int* in_sizes, int n_in,
                              void* d_out, int out_size, void* d_ws, size_t ws_size,
                              hipStream_t stream) {
  const float* hidden = (const float*)d_in[0];
  const float* cosb = (const float*)d_in[1];
  const float* sinb = (const float*)d_in[2];
  const float* qkv_w = (const float*)d_in[3];
  const float* qkv_b = (const float*)d_in[4];
  const float* proj_w = (const float*)d_in[5];
  const float* proj_b = (const float*)d_in[6];

  char* ws = (char*)d_ws;
  short* qkv_bf = (short*)(ws);            // [0, 62.9MB) — written by gemm256
  short* attn_o = (short*)(ws);            // [0, 21MB) — written by attn
  short* wp_bf = (short*)(ws + 23068672);  // inside qkv zone: cast AFTER gemm256
  short* q_bf = (short*)(ws + 125829120);
  short* k_bf = (short*)(ws + 150994944);
  short* v_tb = (short*)(ws + 176160768);
  short* h_bf = (short*)(ws + 197132288);
  short* wq_bf = (short*)(ws + 218103808);

  cast2_f32_bf16<<<2048, 256, 0, stream>>>(hidden, h_bf, (SEQ * DIM) / 4,
                                           qkv_w, wq_bf, (3 * DIM * DIM) / 4);
  gemm256<<<480, 512, 0, stream>>>(h_bf, wq_bf, qkv_b, nullptr, qkv_bf, SEQ, 3 * DIM, DIM);
  rope_qk<<<2560, 256, 0, stream>>>(qkv_bf, cosb, sinb, q_bf, k_bf);
  v_transpose<<<dim3(128, 5, 16), 256, 0, stream>>>(qkv_bf, v_tb);
  cast_f32_bf16<<<1024, 256, 0, stream>>>(proj_w, wp_bf, DIM * DIM);
  attn_kernel<<<1024, 256, 0, stream>>>(q_bf, k_bf, v_tb, attn_o);
  gemm_bt_bias<<<640, 256, 0, stream>>>(attn_o, wp_bf, proj_b, (float*)d_out, nullptr, SEQ, DIM, DIM);
}